// Round 13
// baseline (130.875 us; speedup 1.0000x reference)
//
#include <hip/hip_runtime.h>
#include <hip/hip_bf16.h>

#define EPS 1e-5f

typedef short s16x8 __attribute__((ext_vector_type(8)));
typedef float f32x4 __attribute__((ext_vector_type(4)));

__device__ __forceinline__ unsigned short f2bf(float f) {
    unsigned u = __float_as_uint(f);
    u += 0x7fffu + ((u >> 16) & 1u);
    return (unsigned short)(u >> 16);
}

// ---------------------------------------------------------------------------
// Repack. wp2S: conv2 B in the exact LDS staging image (swizzle baked ->
// kernel staging is a linear copy). wp3: (CO,9,CI). wpL3: LRLC frag-order.
// wf1: conv1 BN-folded scalar table [32][10].
// ---------------------------------------------------------------------------
__global__ __launch_bounds__(256) void repack_w(
    const float* __restrict__ c2w, const float* __restrict__ c3w,
    const float* __restrict__ bw,
    const float* __restrict__ c1w, const float* __restrict__ c1b,
    const float* __restrict__ b1g, const float* __restrict__ b1b,
    const float* __restrict__ b1m, const float* __restrict__ b1v,
    unsigned short* __restrict__ wp2S, unsigned short* __restrict__ wp3,
    unsigned short* __restrict__ wpL3, float* __restrict__ wf1)
{
    int idx = blockIdx.x * 256 + threadIdx.x;
    if (idx < 18432) {                       // conv2 staged image: 2304 ch x 8
        int ch = idx >> 3, e = idx & 7;
        int co = ch / 36, rem = ch % 36;
        int s = rem >> 2, slot = rem & 3;
        int g = slot ^ ((co >> 1) & 3);
        int ci = g * 8 + e;
        wp2S[idx] = f2bf(c2w[(co * 32 + ci) * 9 + s]);
    } else if (idx < 73728) {                // conv3: 96 x 9 x 64
        int i = idx - 18432;
        int co = i / 576, rem = i % 576, s = rem / 64, ci = rem % 64;
        wp3[i] = f2bf(c3w[(co * 64 + ci) * 9 + s]);
    } else if (idx < 516096) {               // lrlc frag-order: 442368 elems
        int i = idx - 73728;
        int e    = i & 7;
        int lane = (i >> 3) & 63;
        int fk   = i >> 9;            // t*3 + kk
        int kk   = fk % 3;
        int t    = fk / 3;            // = (((s*4+cbk)*2+g)*2+rp)*2+j
        int j    = t & 1;
        int rp   = (t >> 1) & 1;
        int g    = (t >> 2) & 1;
        int cbk  = (t >> 3) & 3;
        int s    = t >> 5;
        int col = lane & 15, quad = lane >> 4;
        int cog = (rp * 2 + j) * 128 + cbk * 32 + g * 16 + col;
        int ci  = (kk * 4 + quad) * 8 + e;
        wpL3[i] = f2bf(bw[(cog * 96 + ci) * 9 + s]);
    } else if (idx < 516416) {               // conv1 folded: 32 x 10
        int i = idx - 516096;
        int co = i / 10, k = i % 10;
        float scl = b1g[co] * rsqrtf(b1v[co] + EPS);
        wf1[i] = (k < 9) ? c1w[co * 9 + k] * scl
                         : (c1b[co] - b1m[co]) * scl + b1b[co];
    }
}

// ---------------------------------------------------------------------------
// conv1: x strip in padded LDS; BN-folded weights via uniform s_load path.
// ---------------------------------------------------------------------------
__global__ __launch_bounds__(256) void conv1_s(
    const float* __restrict__ x,      // (64,1,128,128)
    const float* __restrict__ wf1,    // (32,10) folded
    unsigned short* __restrict__ out) // (64,64,64,32) NHWC bf16
{
    __shared__ float xs[10][132];

    const int tid = threadIdx.x;
    const int b = blockIdx.x >> 4, ph4 = blockIdx.x & 15;

    for (int i = tid; i < 10 * 132; i += 256) ((float*)xs)[i] = 0.f;
    __syncthreads();
    const int row0 = ph4 * 8 - 1;
    for (int i = tid; i < 10 * 128; i += 256) {
        int r = i >> 7, c = i & 127;
        int gr = row0 + r;
        if (gr >= 0 && gr < 128)
            xs[r][c + 1] = x[(size_t)b * 16384 + gr * 128 + c];
    }
    __syncthreads();

    const int pw = tid & 63, ph_loc = tid >> 6;
    float pr[4][4];
    #pragma unroll
    for (int rr = 0; rr < 4; ++rr) {
        float2 u0 = *(const float2*)&xs[2 * ph_loc + rr][2 * pw];
        float2 u1 = *(const float2*)&xs[2 * ph_loc + rr][2 * pw + 2];
        pr[rr][0] = u0.x; pr[rr][1] = u0.y; pr[rr][2] = u1.x; pr[rr][3] = u1.y;
    }

    unsigned ow[16];
    #pragma unroll
    for (int co = 0; co < 32; ++co) {
        const float* wv = wf1 + co * 10;
        float a00 = 0.f, a01 = 0.f, a10 = 0.f, a11 = 0.f;
        #pragma unroll
        for (int ky = 0; ky < 3; ++ky)
            #pragma unroll
            for (int kx = 0; kx < 3; ++kx) {
                float wk = wv[ky * 3 + kx];
                a00 = fmaf(wk, pr[ky][kx],         a00);
                a01 = fmaf(wk, pr[ky][kx + 1],     a01);
                a10 = fmaf(wk, pr[ky + 1][kx],     a10);
                a11 = fmaf(wk, pr[ky + 1][kx + 1], a11);
            }
        float o = fmaxf(fmaxf(fmaxf(a00, a01), fmaxf(a10, a11)) + wv[9], 0.f);
        unsigned u = (unsigned)f2bf(o);
        if ((co & 1) == 0) ow[co >> 1] = u;
        else               ow[co >> 1] |= u << 16;
    }

    const int PH = ph4 * 4 + ph_loc;
    unsigned short* dst = out + (((size_t)(b * 64 + PH)) * 64 + pw) * 32;
    #pragma unroll
    for (int q = 0; q < 4; ++q) {
        uint4 v = make_uint4(ow[q * 4], ow[q * 4 + 1], ow[q * 4 + 2], ow[q * 4 + 3]);
        *(uint4*)(dst + q * 8) = v;
    }
}

// ---------------------------------------------------------------------------
// Fused implicit-GEMM conv3x3 + BN + ReLU + pool2x2 via bf16 MFMA.
// LINB: B staging is a linear copy from a pre-baked image.
// ---------------------------------------------------------------------------
template<int CI, int CO, int W, int NWM, int NWN, bool ALLB, bool LINB,
         int SASH, int SAMK, int SBSH, int SBMK>
__global__ __launch_bounds__(256) void conv_mfma_pool(
    const unsigned short* __restrict__ xin,
    const unsigned short* __restrict__ wpk,
    const float* __restrict__ cbv, const float* __restrict__ gg,
    const float* __restrict__ bnb, const float* __restrict__ mm,
    const float* __restrict__ vv,
    unsigned short* __restrict__ out)
{
    constexpr int WT  = W + 2;
    constexpr int NFW = CO / 16 / NWN;
    constexpr int CG  = CI / 8;
    constexpr int ASZ = 4 * WT * CI * 2;
    constexpr int BSZ = (ALLB ? 9 : 1) * CO * CI * 2;
    constexpr int KSTEPS = CI / 32;
    constexpr int PH2 = W / 2;
    constexpr int HPX = PH2 / 8;

    __shared__ __align__(16) unsigned char sm[ASZ + BSZ];

    const int tid = threadIdx.x;
    const int wave = tid >> 6, lane = tid & 63;
    const int quad = lane >> 4, col = lane & 15;
    const int wm = wave % NWM, wn = wave / NWM;

    const int xcd  = blockIdx.x & 7;
    const int slot = blockIdx.x >> 3;
    const int hp = xcd * HPX + (slot % HPX);
    const int b  = slot / HPX;

    constexpr int NCHA = 4 * WT * CG;
    for (int ch = tid; ch < NCHA; ch += 256) {
        int r    = ch / (WT * CG);
        int rem  = ch % (WT * CG);
        int wp   = rem / CG;
        int slot_ = rem % CG;
        int g = slot_ ^ ((wp >> SASH) & SAMK);
        int h = hp * 2 - 1 + r;
        int w = wp - 1;
        s16x8 val = {};
        if (h >= 0 && h < W && w >= 0 && w < W)
            val = *(const s16x8*)(xin + (((size_t)(b * W + h) * W + w) * CI + g * 8));
        *(s16x8*)(sm + ch * 16) = val;
    }
    if constexpr (ALLB) {
        constexpr int NCHB = CO * 9 * CG;
        if constexpr (LINB) {
            for (int ch = tid; ch < NCHB; ch += 256)
                *(s16x8*)(sm + ASZ + ch * 16) = *(const s16x8*)(wpk + ch * 8);
        } else {
            for (int ch = tid; ch < NCHB; ch += 256) {
                int co   = ch / (9 * CG);
                int rem  = ch % (9 * CG);
                int s    = rem / CG;
                int slot_ = rem % CG;
                int g = slot_ ^ ((co >> SBSH) & SBMK);
                s16x8 val = *(const s16x8*)(wpk + ((co * 9 + s) * CI + g * 8));
                *(s16x8*)(sm + ASZ + ch * 16) = val;
            }
        }
        __syncthreads();
    }

    f32x4 acc[2][NFW];
    #pragma unroll
    for (int i = 0; i < 2; ++i)
        #pragma unroll
        for (int j = 0; j < NFW; ++j) acc[i][j] = (f32x4){0.f, 0.f, 0.f, 0.f};

    #pragma unroll
    for (int s = 0; s < 9; ++s) {
        const int dy = s / 3, dx = s % 3;
        if constexpr (!ALLB) {
            __syncthreads();
            constexpr int NCHB = CO * CG;
            for (int ch = tid; ch < NCHB; ch += 256) {
                int co = ch / CG, slot_ = ch % CG;
                int g = slot_ ^ ((co >> SBSH) & SBMK);
                s16x8 val = *(const s16x8*)(wpk + ((co * 9 + s) * CI + g * 8));
                *(s16x8*)(sm + ASZ + ch * 16) = val;
            }
            __syncthreads();
        }
        #pragma unroll
        for (int kk = 0; kk < KSTEPS; ++kk) {
            const int g = kk * 4 + quad;
            s16x8 a[2];
            #pragma unroll
            for (int mi = 0; mi < 2; ++mi) {
                int wp = wm * 16 + col + dx;
                int r  = mi + dy;
                int addr = (r * WT + wp) * (CI * 2) + ((g ^ ((wp >> SASH) & SAMK)) << 4);
                a[mi] = *(const s16x8*)(sm + addr);
            }
            #pragma unroll
            for (int nf = 0; nf < NFW; ++nf) {
                int co_l = (wn * NFW + nf) * 16 + col;
                int row = ALLB ? (co_l * 9 + s) : co_l;
                int addr = ASZ + row * (CI * 2) + ((g ^ ((co_l >> SBSH) & SBMK)) << 4);
                s16x8 bf = *(const s16x8*)(sm + addr);
                acc[0][nf] = __builtin_amdgcn_mfma_f32_16x16x32_bf16(a[0], bf, acc[0][nf], 0, 0, 0);
                acc[1][nf] = __builtin_amdgcn_mfma_f32_16x16x32_bf16(a[1], bf, acc[1][nf], 0, 0, 0);
            }
        }
    }

    #pragma unroll
    for (int nf = 0; nf < NFW; ++nf) {
        int co = (wn * NFW + nf) * 16 + col;
        float scl = gg[co] * rsqrtf(vv[co] + EPS);
        float sh  = (cbv[co] - mm[co]) * scl + bnb[co];
        #pragma unroll
        for (int pr = 0; pr < 2; ++pr) {
            float y0 = fmaf(acc[0][nf][2 * pr],     scl, sh);
            float y1 = fmaf(acc[0][nf][2 * pr + 1], scl, sh);
            float y2 = fmaf(acc[1][nf][2 * pr],     scl, sh);
            float y3 = fmaf(acc[1][nf][2 * pr + 1], scl, sh);
            float o = fmaxf(fmaxf(fmaxf(y0, y1), fmaxf(y2, y3)), 0.f);
            int pw = wm * 8 + quad * 2 + pr;
            out[((size_t)(b * PH2 + hp) * PH2 + pw) * CO + co] = f2bf(o);
        }
    }
}

// ---------------------------------------------------------------------------
// LRLC v4: B per-wave from fragment-ordered wpL3 (no B-LDS, 3 barriers).
// ---------------------------------------------------------------------------
__global__ __launch_bounds__(512) void lrlc_mfma4(
    const unsigned short* __restrict__ xin,  // (64,16,16,96) bf16
    const unsigned short* __restrict__ wpk3, // frag-ordered (442368)
    const float* __restrict__ bbias,         // (4,128)
    const float* __restrict__ cwh, const float* __restrict__ cww,
    unsigned short* __restrict__ actB)       // (64, 32768) bf16
{
    constexpr int CI = 96, WT = 18, NR = 10, CG = 12;
    constexpr int ASZ = NR * WT * CI * 2;    // 34560 B
    __shared__ __align__(16) unsigned char sm[ASZ];
    __shared__ float cwt[256][4];

    const int tid = threadIdx.x;
    const int wave = tid >> 6, lane = tid & 63;
    const int quad = lane >> 4, col = lane & 15;
    const int wm = wave & 1;
    const int g  = (wave >> 1) & 1;
    const int rp = wave >> 2;

    const int cbk = blockIdx.x & 3;
    const int mb  = (blockIdx.x >> 2) & 1;
    const int b   = blockIdx.x >> 3;

    if (tid < 256) {
        int h = tid >> 4, w = tid & 15;
        float e[4], mx = -1e30f;
        #pragma unroll
        for (int r = 0; r < 4; ++r) { e[r] = cwh[h * 4 + r] + cww[w * 4 + r]; mx = fmaxf(mx, e[r]); }
        float se = 0.f;
        #pragma unroll
        for (int r = 0; r < 4; ++r) { e[r] = expf(e[r] - mx); se += e[r]; }
        float inv = 1.f / se;
        #pragma unroll
        for (int r = 0; r < 4; ++r) cwt[tid][r] = e[r] * inv;
    }

    constexpr int NCHA = NR * WT * CG;  // 2160
    for (int ch = tid; ch < NCHA; ch += 512) {
        int r    = ch / (WT * CG);
        int rem  = ch % (WT * CG);
        int wp   = rem / CG, slot = rem % CG;
        int gg_ = slot ^ ((wp >> 1) & 3);
        int h = mb * 8 + r - 1;
        int w = wp - 1;
        s16x8 val = {};
        if (h >= 0 && h < 16 && w >= 0 && w < 16)
            val = *(const s16x8*)(xin + (((size_t)(b * 16 + h) * 16 + w) * CI + gg_ * 8));
        *(s16x8*)(sm + ch * 16) = val;
    }
    __syncthreads();

    f32x4 acc[4][2];
    #pragma unroll
    for (int i = 0; i < 4; ++i)
        #pragma unroll
        for (int j = 0; j < 2; ++j) acc[i][j] = (f32x4){0.f, 0.f, 0.f, 0.f};

    const int tbase = ((cbk * 2 + g) * 2 + rp);
    for (int s = 0; s < 9; ++s) {
        const int dy = s / 3, dx = s % 3;
        s16x8 bf[2][3];
        #pragma unroll
        for (int j = 0; j < 2; ++j)
            #pragma unroll
            for (int kk = 0; kk < 3; ++kk) {
                int fidx = ((s * 32 + tbase * 2 + j) * 3 + kk) * 512 + lane * 8;
                bf[j][kk] = *(const s16x8*)(wpk3 + fidx);
            }
        #pragma unroll
        for (int kk = 0; kk < 3; ++kk) {
            const int gg = kk * 4 + quad;
            s16x8 a[4];
            #pragma unroll
            for (int mi = 0; mi < 4; ++mi) {
                int mf = wm * 4 + mi;
                int r  = mf + dy;
                int wp = col + dx;
                int addr = (r * WT + wp) * (CI * 2) + ((gg ^ ((wp >> 1) & 3)) << 4);
                a[mi] = *(const s16x8*)(sm + addr);
            }
            #pragma unroll
            for (int mi = 0; mi < 4; ++mi)
                #pragma unroll
                for (int j = 0; j < 2; ++j)
                    acc[mi][j] = __builtin_amdgcn_mfma_f32_16x16x32_bf16(
                        a[mi], bf[j][kk], acc[mi][j], 0, 0, 0);
        }
    }
    __syncthreads();

    float* ldo = (float*)sm;   // [2][128][33]
    {
        const int c_lo = g * 16 + col;
        const int cg   = cbk * 32 + c_lo;
        float bbA = bbias[(rp * 2 + 0) * 128 + cg];
        float bbB = bbias[(rp * 2 + 1) * 128 + cg];
        #pragma unroll
        for (int mi = 0; mi < 4; ++mi) {
            int mf = wm * 4 + mi;
            #pragma unroll
            for (int rg = 0; rg < 4; ++rg) {
                int hwl = mf * 16 + quad * 4 + rg;
                int hwg = mb * 128 + hwl;
                float o = cwt[hwg][rp * 2]     * (acc[mi][0][rg] + bbA)
                        + cwt[hwg][rp * 2 + 1] * (acc[mi][1][rg] + bbB);
                ldo[(rp * 128 + hwl) * 33 + c_lo] = o;
            }
        }
    }
    __syncthreads();
    {
        int cl = tid >> 4;
        int sg = tid & 15;
        size_t base = (size_t)b * 32768 + (cbk * 32 + cl) * 256 + mb * 128 + sg * 8;
        s16x8 v;
        #pragma unroll
        for (int i = 0; i < 8; ++i) {
            int hw = sg * 8 + i;
            float o = ldo[hw * 33 + cl] + ldo[(128 + hw) * 33 + cl];
            v[i] = (short)f2bf(fmaxf(o, 0.f));
        }
        *(s16x8*)(actB + base) = v;
    }
}

// ---------------------------------------------------------------------------
// fc1 v2: Wl-only LDS (32 KB -> 4+ blocks/CU); act B-fragments read directly
// from global (L2-resident, lrlc_mfma4-proven gather pattern); one 256-k
// chunk per block, single barrier. grid = 8 xcd x 16 ks x 8 jt = 1024.
// ---------------------------------------------------------------------------
__global__ __launch_bounds__(256) void fc1_v2(
    const unsigned short* __restrict__ actB, // (64, 32768) bf16
    const float* __restrict__ w,             // (512, 32768) f32
    float* __restrict__ partial)             // (128, 512, 64)
{
    __shared__ __align__(16) unsigned short Wl[64 * 256];   // 32 KB

    const int tid = threadIdx.x;
    const int wave = tid >> 6, lane = tid & 63;
    const int quad = lane >> 4, col = lane & 15;
    const int wm = wave & 1, wn = wave >> 1;
    const int xcd  = blockIdx.x & 7;
    const int slot = blockIdx.x >> 3;        // 0..127
    const int ks = xcd * 16 + (slot >> 3);   // 0..127
    const int jt = slot & 7;
    const int k0 = ks * 256;

    const int rt = tid >> 2, seg = tid & 3;
    const float* wsrc = w + (size_t)(jt * 64 + rt) * 32768 + k0 + seg * 64;

    // stage W chunk (256 B contiguous per thread), f32->bf16, XOR swizzle
    #pragma unroll
    for (int u = 0; u < 8; ++u) {
        float4 f0 = *(const float4*)(wsrc + u * 8);
        float4 f1 = *(const float4*)(wsrc + u * 8 + 4);
        s16x8 v;
        v[0] = (short)f2bf(f0.x); v[1] = (short)f2bf(f0.y);
        v[2] = (short)f2bf(f0.z); v[3] = (short)f2bf(f0.w);
        v[4] = (short)f2bf(f1.x); v[5] = (short)f2bf(f1.y);
        v[6] = (short)f2bf(f1.z); v[7] = (short)f2bf(f1.w);
        int phys = (seg * 8 + u) ^ (rt & 7);
        *(s16x8*)(Wl + rt * 256 + phys * 8) = v;
    }
    __syncthreads();

    f32x4 acc[2][2];
    #pragma unroll
    for (int i = 0; i < 2; ++i)
        #pragma unroll
        for (int j = 0; j < 2; ++j) acc[i][j] = (f32x4){0.f, 0.f, 0.f, 0.f};

    const unsigned short* abase = actB + k0;
    #pragma unroll
    for (int kk = 0; kk < 8; ++kk) {
        const int gg = kk * 4 + quad;
        s16x8 a[2], bb[2];
        #pragma unroll
        for (int mf = 0; mf < 2; ++mf) {
            int j_l = wm * 32 + mf * 16 + col;
            a[mf] = *(const s16x8*)(Wl + j_l * 256 + ((gg ^ (j_l & 7)) << 3));
        }
        #pragma unroll
        for (int bg = 0; bg < 2; ++bg) {
            int b_l = wn * 32 + bg * 16 + col;
            bb[bg] = *(const s16x8*)(abase + (size_t)b_l * 32768 + gg * 8);
        }
        #pragma unroll
        for (int mf = 0; mf < 2; ++mf)
            #pragma unroll
            for (int bg = 0; bg < 2; ++bg)
                acc[mf][bg] = __builtin_amdgcn_mfma_f32_16x16x32_bf16(
                    a[mf], bb[bg], acc[mf][bg], 0, 0, 0);
    }
    #pragma unroll
    for (int mf = 0; mf < 2; ++mf)
        #pragma unroll
        for (int bg = 0; bg < 2; ++bg)
            #pragma unroll
            for (int r = 0; r < 4; ++r) {
                int j = jt * 64 + wm * 32 + mf * 16 + quad * 4 + r;
                int b = wn * 32 + bg * 16 + col;
                partial[((size_t)ks * 512 + j) * 64 + b] = acc[mf][bg][r];
            }
}

__global__ __launch_bounds__(256) void fc1_reduce5(
    const float* __restrict__ partial, const float* __restrict__ bias,
    float* __restrict__ out)             // (64,512)
{
    int idx = blockIdx.x * 256 + threadIdx.x;
    int b = idx & 63, j = idx >> 6;
    float a = bias[j];
    #pragma unroll 8
    for (int ks = 0; ks < 128; ++ks)
        a += partial[((size_t)ks * 512 + j) * 64 + b];
    out[b * 512 + j] = fmaxf(a, 0.f);
}

__global__ __launch_bounds__(256) void fc2_kernel(
    const float* __restrict__ x,    // (64, 512)
    const float* __restrict__ w,    // (10, 512)
    const float* __restrict__ bias,
    float* __restrict__ out)        // (64, 10)
{
    int idx = blockIdx.x * 256 + threadIdx.x;
    if (idx >= 640) return;
    int n = idx % 10, b = idx / 10;
    float a = bias[n];
    const float* xr = x + b * 512;
    const float* wr = w + n * 512;
    for (int j = 0; j < 512; ++j) a = fmaf(xr[j], wr[j], a);
    out[idx] = a;
}

// ---------------------------------------------------------------------------
extern "C" void kernel_launch(void* const* d_in, const int* in_sizes, int n_in,
                              void* d_out, int out_size, void* d_ws, size_t ws_size,
                              hipStream_t stream) {
    const float* x   = (const float*)d_in[0];
    const float* c1w = (const float*)d_in[1];  const float* c1b = (const float*)d_in[2];
    const float* b1g = (const float*)d_in[3];  const float* b1b = (const float*)d_in[4];
    const float* b1m = (const float*)d_in[5];  const float* b1v = (const float*)d_in[6];
    const float* c2w = (const float*)d_in[7];  const float* c2b = (const float*)d_in[8];
    const float* b2g = (const float*)d_in[9];  const float* b2b = (const float*)d_in[10];
    const float* b2m = (const float*)d_in[11]; const float* b2v = (const float*)d_in[12];
    const float* c3w = (const float*)d_in[13]; const float* c3b = (const float*)d_in[14];
    const float* b3g = (const float*)d_in[15]; const float* b3b = (const float*)d_in[16];
    const float* b3m = (const float*)d_in[17]; const float* b3v = (const float*)d_in[18];
    const float* bw  = (const float*)d_in[19]; const float* bb  = (const float*)d_in[20];
    const float* cwh = (const float*)d_in[21]; const float* cww = (const float*)d_in[22];
    const float* f1w = (const float*)d_in[23]; const float* f1b = (const float*)d_in[24];
    const float* f2w = (const float*)d_in[25]; const float* f2b = (const float*)d_in[26];
    float* out = (float*)d_out;

    char* ws = (char*)d_ws;
    unsigned short* act1 = (unsigned short*)(ws + 0);           // [0,16M)
    unsigned short* act2 = (unsigned short*)(ws + 16777216);    // [16M,24M) dead before fc1
    unsigned short* act3 = (unsigned short*)(ws + 0);           // [0,3M)   (act1 dead)
    unsigned short* actB = (unsigned short*)(ws + 4194304);     // [4M,8M)
    float*          part = (float*)(ws + 8388608);              // [8M,24M) 128x512x64
    float*          fc1o = (float*)(ws + 0);                    // [0,128K) (act3 dead)
    unsigned short* wp2S = (unsigned short*)(ws + 25165824);    //  36,864 B
    unsigned short* wp3  = (unsigned short*)(ws + 25202688);    // 110,592 B
    unsigned short* wpL3 = (unsigned short*)(ws + 25313280);    // 884,736 B
    float*          wf1  = (float*)(ws + 26198016);             //   1,280 B

    repack_w<<<2018, 256, 0, stream>>>(c2w, c3w, bw, c1w, c1b, b1g, b1b, b1m, b1v,
                                       wp2S, wp3, wpL3, wf1);

    conv1_s<<<1024, 256, 0, stream>>>(x, wf1, act1);

    conv_mfma_pool<32, 64, 64, 4, 1, true, true, 1, 3, 1, 3>
        <<<2048, 256, 0, stream>>>(act1, wp2S, c2b, b2g, b2b, b2m, b2v, act2);

    conv_mfma_pool<64, 96, 32, 2, 2, false, false, 0, 7, 0, 7>
        <<<1024, 256, 0, stream>>>(act2, wp3, c3b, b3g, b3b, b3m, b3v, act3);

    lrlc_mfma4<<<512, 512, 0, stream>>>(act3, wpL3, bb, cwh, cww, actB);

    fc1_v2<<<1024, 256, 0, stream>>>(actB, f1w, part);
    fc1_reduce5<<<128, 256, 0, stream>>>(part, f1b, fc1o);
    fc2_kernel<<<3, 256, 0, stream>>>(fc1o, f2w, f2b, out);
}

// Round 14
// 118.308 us; speedup vs baseline: 1.1062x; 1.1062x over previous
//
#include <hip/hip_runtime.h>
#include <hip/hip_bf16.h>

#define EPS 1e-5f

typedef short s16x8 __attribute__((ext_vector_type(8)));
typedef float f32x4 __attribute__((ext_vector_type(4)));

__device__ __forceinline__ unsigned short f2bf(float f) {
    unsigned u = __float_as_uint(f);
    u += 0x7fffu + ((u >> 16) & 1u);
    return (unsigned short)(u >> 16);
}

// ---------------------------------------------------------------------------
// Repack. wp2S: conv2 B LDS-image (linear-copy staging). wp3F: conv3 B in
// MFMA fragment order [(s,kk,cog)][lane][8] (same range as old wp3).
// wpL3: LRLC frag-order. wf1: conv1 BN-folded [32][10].
// ---------------------------------------------------------------------------
__global__ __launch_bounds__(256) void repack_w(
    const float* __restrict__ c2w, const float* __restrict__ c3w,
    const float* __restrict__ bw,
    const float* __restrict__ c1w, const float* __restrict__ c1b,
    const float* __restrict__ b1g, const float* __restrict__ b1b,
    const float* __restrict__ b1m, const float* __restrict__ b1v,
    unsigned short* __restrict__ wp2S, unsigned short* __restrict__ wp3F,
    unsigned short* __restrict__ wpL3, float* __restrict__ wf1)
{
    int idx = blockIdx.x * 256 + threadIdx.x;
    if (idx < 18432) {                       // conv2 staged image: 2304 ch x 8
        int ch = idx >> 3, e = idx & 7;
        int co = ch / 36, rem = ch % 36;
        int s = rem >> 2, slot = rem & 3;
        int g = slot ^ ((co >> 1) & 3);
        int ci = g * 8 + e;
        wp2S[idx] = f2bf(c2w[(co * 32 + ci) * 9 + s]);
    } else if (idx < 73728) {                // conv3 frag-order: 108 frags x 512
        int i = idx - 18432;
        int e    = i & 7;
        int lane = (i >> 3) & 63;
        int f    = i >> 9;            // (s*2+kk)*6 + cg
        int cg   = f % 6;
        int t2   = f / 6;
        int kk   = t2 & 1;
        int s    = t2 >> 1;
        int col = lane & 15, quad = lane >> 4;
        int co = cg * 16 + col;
        int ci = (kk * 4 + quad) * 8 + e;
        wp3F[i] = f2bf(c3w[(co * 64 + ci) * 9 + s]);
    } else if (idx < 516096) {               // lrlc frag-order: 442368 elems
        int i = idx - 73728;
        int e    = i & 7;
        int lane = (i >> 3) & 63;
        int fk   = i >> 9;            // t*3 + kk
        int kk   = fk % 3;
        int t    = fk / 3;            // = (((s*4+cbk)*2+g)*2+rp)*2+j
        int j    = t & 1;
        int rp   = (t >> 1) & 1;
        int g    = (t >> 2) & 1;
        int cbk  = (t >> 3) & 3;
        int s    = t >> 5;
        int col = lane & 15, quad = lane >> 4;
        int cog = (rp * 2 + j) * 128 + cbk * 32 + g * 16 + col;
        int ci  = (kk * 4 + quad) * 8 + e;
        wpL3[i] = f2bf(bw[(cog * 96 + ci) * 9 + s]);
    } else if (idx < 516416) {               // conv1 folded: 32 x 10
        int i = idx - 516096;
        int co = i / 10, k = i % 10;
        float scl = b1g[co] * rsqrtf(b1v[co] + EPS);
        wf1[i] = (k < 9) ? c1w[co * 9 + k] * scl
                         : (c1b[co] - b1m[co]) * scl + b1b[co];
    }
}

// ---------------------------------------------------------------------------
// conv1: x strip in padded LDS; BN-folded weights via uniform s_load path.
// ---------------------------------------------------------------------------
__global__ __launch_bounds__(256) void conv1_s(
    const float* __restrict__ x,      // (64,1,128,128)
    const float* __restrict__ wf1,    // (32,10) folded
    unsigned short* __restrict__ out) // (64,64,64,32) NHWC bf16
{
    __shared__ float xs[10][132];

    const int tid = threadIdx.x;
    const int b = blockIdx.x >> 4, ph4 = blockIdx.x & 15;

    for (int i = tid; i < 10 * 132; i += 256) ((float*)xs)[i] = 0.f;
    __syncthreads();
    const int row0 = ph4 * 8 - 1;
    for (int i = tid; i < 10 * 128; i += 256) {
        int r = i >> 7, c = i & 127;
        int gr = row0 + r;
        if (gr >= 0 && gr < 128)
            xs[r][c + 1] = x[(size_t)b * 16384 + gr * 128 + c];
    }
    __syncthreads();

    const int pw = tid & 63, ph_loc = tid >> 6;
    float pr[4][4];
    #pragma unroll
    for (int rr = 0; rr < 4; ++rr) {
        float2 u0 = *(const float2*)&xs[2 * ph_loc + rr][2 * pw];
        float2 u1 = *(const float2*)&xs[2 * ph_loc + rr][2 * pw + 2];
        pr[rr][0] = u0.x; pr[rr][1] = u0.y; pr[rr][2] = u1.x; pr[rr][3] = u1.y;
    }

    unsigned ow[16];
    #pragma unroll
    for (int co = 0; co < 32; ++co) {
        const float* wv = wf1 + co * 10;
        float a00 = 0.f, a01 = 0.f, a10 = 0.f, a11 = 0.f;
        #pragma unroll
        for (int ky = 0; ky < 3; ++ky)
            #pragma unroll
            for (int kx = 0; kx < 3; ++kx) {
                float wk = wv[ky * 3 + kx];
                a00 = fmaf(wk, pr[ky][kx],         a00);
                a01 = fmaf(wk, pr[ky][kx + 1],     a01);
                a10 = fmaf(wk, pr[ky + 1][kx],     a10);
                a11 = fmaf(wk, pr[ky + 1][kx + 1], a11);
            }
        float o = fmaxf(fmaxf(fmaxf(a00, a01), fmaxf(a10, a11)) + wv[9], 0.f);
        unsigned u = (unsigned)f2bf(o);
        if ((co & 1) == 0) ow[co >> 1] = u;
        else               ow[co >> 1] |= u << 16;
    }

    const int PH = ph4 * 4 + ph_loc;
    unsigned short* dst = out + (((size_t)(b * 64 + PH)) * 64 + pw) * 32;
    #pragma unroll
    for (int q = 0; q < 4; ++q) {
        uint4 v = make_uint4(ow[q * 4], ow[q * 4 + 1], ow[q * 4 + 2], ow[q * 4 + 3]);
        *(uint4*)(dst + q * 8) = v;
    }
}

// ---------------------------------------------------------------------------
// conv2: fused implicit-GEMM conv3x3 + BN + ReLU + pool2x2, all-shift B
// staged via linear copy from wp2S. XCD-aware hp mapping.
// ---------------------------------------------------------------------------
__global__ __launch_bounds__(256) void conv2_mfma(
    const unsigned short* __restrict__ xin,  // (64,64,64,32)
    const unsigned short* __restrict__ wp2S, // staged image 18432
    const float* __restrict__ cbv, const float* __restrict__ gg,
    const float* __restrict__ bnb, const float* __restrict__ mm,
    const float* __restrict__ vv,
    unsigned short* __restrict__ out)        // (64,32,32,64)
{
    constexpr int CI = 32, CO = 64, W = 64, WT = 66, CG = 4;
    constexpr int ASZ = 4 * WT * CI * 2;     // 16896
    constexpr int BSZ = 9 * CO * CI * 2;     // 36864
    constexpr int PH2 = 32, HPX = 4;

    __shared__ __align__(16) unsigned char sm[ASZ + BSZ];

    const int tid = threadIdx.x;
    const int wave = tid >> 6, lane = tid & 63;
    const int quad = lane >> 4, col = lane & 15;
    const int wm = wave;                     // NWM=4, NWN=1

    const int xcd  = blockIdx.x & 7;
    const int slot = blockIdx.x >> 3;
    const int hp = xcd * HPX + (slot % HPX);
    const int b  = slot / HPX;

    constexpr int NCHA = 4 * WT * CG;
    for (int ch = tid; ch < NCHA; ch += 256) {
        int r    = ch / (WT * CG);
        int rem  = ch % (WT * CG);
        int wp   = rem / CG;
        int slot_ = rem % CG;
        int g = slot_ ^ ((wp >> 1) & 3);
        int h = hp * 2 - 1 + r;
        int w = wp - 1;
        s16x8 val = {};
        if (h >= 0 && h < W && w >= 0 && w < W)
            val = *(const s16x8*)(xin + (((size_t)(b * W + h) * W + w) * CI + g * 8));
        *(s16x8*)(sm + ch * 16) = val;
    }
    for (int ch = tid; ch < 2304; ch += 256)
        *(s16x8*)(sm + ASZ + ch * 16) = *(const s16x8*)(wp2S + ch * 8);
    __syncthreads();

    f32x4 acc[2][4];
    #pragma unroll
    for (int i = 0; i < 2; ++i)
        #pragma unroll
        for (int j = 0; j < 4; ++j) acc[i][j] = (f32x4){0.f, 0.f, 0.f, 0.f};

    #pragma unroll
    for (int s = 0; s < 9; ++s) {
        const int dy = s / 3, dx = s % 3;
        const int g = quad;
        s16x8 a[2];
        #pragma unroll
        for (int mi = 0; mi < 2; ++mi) {
            int wp = wm * 16 + col + dx;
            int r  = mi + dy;
            int addr = (r * WT + wp) * (CI * 2) + ((g ^ ((wp >> 1) & 3)) << 4);
            a[mi] = *(const s16x8*)(sm + addr);
        }
        #pragma unroll
        for (int nf = 0; nf < 4; ++nf) {
            int co_l = nf * 16 + col;
            int row = co_l * 9 + s;
            int addr = ASZ + row * (CI * 2) + ((g ^ ((co_l >> 1) & 3)) << 4);
            s16x8 bf = *(const s16x8*)(sm + addr);
            acc[0][nf] = __builtin_amdgcn_mfma_f32_16x16x32_bf16(a[0], bf, acc[0][nf], 0, 0, 0);
            acc[1][nf] = __builtin_amdgcn_mfma_f32_16x16x32_bf16(a[1], bf, acc[1][nf], 0, 0, 0);
        }
    }

    #pragma unroll
    for (int nf = 0; nf < 4; ++nf) {
        int co = nf * 16 + col;
        float scl = gg[co] * rsqrtf(vv[co] + EPS);
        float sh  = (cbv[co] - mm[co]) * scl + bnb[co];
        #pragma unroll
        for (int pr = 0; pr < 2; ++pr) {
            float y0 = fmaf(acc[0][nf][2 * pr],     scl, sh);
            float y1 = fmaf(acc[0][nf][2 * pr + 1], scl, sh);
            float y2 = fmaf(acc[1][nf][2 * pr],     scl, sh);
            float y3 = fmaf(acc[1][nf][2 * pr + 1], scl, sh);
            float o = fmaxf(fmaxf(fmaxf(y0, y1), fmaxf(y2, y3)), 0.f);
            int pw = wm * 8 + quad * 2 + pr;
            out[((size_t)(b * PH2 + hp) * PH2 + pw) * CO + co] = f2bf(o);
        }
    }
}

// ---------------------------------------------------------------------------
// conv3 v2: B per-wave from fragment-ordered wp3F (no B-LDS, 1 barrier).
// A in LDS. Waves 2x2 (wm M-half, wn co-group), NFW=3, KSTEPS=2.
// ---------------------------------------------------------------------------
__global__ __launch_bounds__(256) void conv3_mfma(
    const unsigned short* __restrict__ xin,  // (64,32,32,64)
    const unsigned short* __restrict__ wp3F, // frag-ordered 55296
    const float* __restrict__ cbv, const float* __restrict__ gg,
    const float* __restrict__ bnb, const float* __restrict__ mm,
    const float* __restrict__ vv,
    unsigned short* __restrict__ out)        // (64,16,16,96)
{
    constexpr int CI = 64, CO = 96, W = 32, WT = 34, CG = 8;
    constexpr int ASZ = 4 * WT * CI * 2;     // 17408
    constexpr int PH2 = 16, HPX = 2;

    __shared__ __align__(16) unsigned char sm[ASZ];

    const int tid = threadIdx.x;
    const int wave = tid >> 6, lane = tid & 63;
    const int quad = lane >> 4, col = lane & 15;
    const int wm = wave & 1, wn = wave >> 1;

    const int xcd  = blockIdx.x & 7;
    const int slot = blockIdx.x >> 3;
    const int hp = xcd * HPX + (slot % HPX);
    const int b  = slot / HPX;

    constexpr int NCHA = 4 * WT * CG;   // 1088
    for (int ch = tid; ch < NCHA; ch += 256) {
        int r    = ch / (WT * CG);
        int rem  = ch % (WT * CG);
        int wp   = rem / CG;
        int slot_ = rem % CG;
        int g = slot_ ^ (wp & 7);
        int h = hp * 2 - 1 + r;
        int w = wp - 1;
        s16x8 val = {};
        if (h >= 0 && h < W && w >= 0 && w < W)
            val = *(const s16x8*)(xin + (((size_t)(b * W + h) * W + w) * CI + g * 8));
        *(s16x8*)(sm + ch * 16) = val;
    }
    __syncthreads();

    f32x4 acc[2][3];
    #pragma unroll
    for (int i = 0; i < 2; ++i)
        #pragma unroll
        for (int j = 0; j < 3; ++j) acc[i][j] = (f32x4){0.f, 0.f, 0.f, 0.f};

    for (int s = 0; s < 9; ++s) {
        const int dy = s / 3, dx = s % 3;
        s16x8 bf[3][2];
        #pragma unroll
        for (int nf = 0; nf < 3; ++nf)
            #pragma unroll
            for (int kk = 0; kk < 2; ++kk) {
                int fidx = (((s * 2 + kk) * 6) + wn * 3 + nf) * 512 + lane * 8;
                bf[nf][kk] = *(const s16x8*)(wp3F + fidx);
            }
        #pragma unroll
        for (int kk = 0; kk < 2; ++kk) {
            const int g = kk * 4 + quad;
            s16x8 a[2];
            #pragma unroll
            for (int mi = 0; mi < 2; ++mi) {
                int wp = wm * 16 + col + dx;
                int r  = mi + dy;
                int addr = (r * WT + wp) * (CI * 2) + ((g ^ (wp & 7)) << 4);
                a[mi] = *(const s16x8*)(sm + addr);
            }
            #pragma unroll
            for (int nf = 0; nf < 3; ++nf) {
                acc[0][nf] = __builtin_amdgcn_mfma_f32_16x16x32_bf16(a[0], bf[nf][kk], acc[0][nf], 0, 0, 0);
                acc[1][nf] = __builtin_amdgcn_mfma_f32_16x16x32_bf16(a[1], bf[nf][kk], acc[1][nf], 0, 0, 0);
            }
        }
    }

    #pragma unroll
    for (int nf = 0; nf < 3; ++nf) {
        int co = (wn * 3 + nf) * 16 + col;
        float scl = gg[co] * rsqrtf(vv[co] + EPS);
        float sh  = (cbv[co] - mm[co]) * scl + bnb[co];
        #pragma unroll
        for (int pr = 0; pr < 2; ++pr) {
            float y0 = fmaf(acc[0][nf][2 * pr],     scl, sh);
            float y1 = fmaf(acc[0][nf][2 * pr + 1], scl, sh);
            float y2 = fmaf(acc[1][nf][2 * pr],     scl, sh);
            float y3 = fmaf(acc[1][nf][2 * pr + 1], scl, sh);
            float o = fmaxf(fmaxf(fmaxf(y0, y1), fmaxf(y2, y3)), 0.f);
            int pw = wm * 8 + quad * 2 + pr;
            out[((size_t)(b * PH2 + hp) * PH2 + pw) * CO + co] = f2bf(o);
        }
    }
}

// ---------------------------------------------------------------------------
// LRLC v4: B per-wave from fragment-ordered wpL3 (no B-LDS, 3 barriers).
// ---------------------------------------------------------------------------
__global__ __launch_bounds__(512) void lrlc_mfma4(
    const unsigned short* __restrict__ xin,  // (64,16,16,96) bf16
    const unsigned short* __restrict__ wpk3, // frag-ordered (442368)
    const float* __restrict__ bbias,         // (4,128)
    const float* __restrict__ cwh, const float* __restrict__ cww,
    unsigned short* __restrict__ actB)       // (64, 32768) bf16
{
    constexpr int CI = 96, WT = 18, NR = 10, CG = 12;
    constexpr int ASZ = NR * WT * CI * 2;    // 34560 B
    __shared__ __align__(16) unsigned char sm[ASZ];
    __shared__ float cwt[256][4];

    const int tid = threadIdx.x;
    const int wave = tid >> 6, lane = tid & 63;
    const int quad = lane >> 4, col = lane & 15;
    const int wm = wave & 1;
    const int g  = (wave >> 1) & 1;
    const int rp = wave >> 2;

    const int cbk = blockIdx.x & 3;
    const int mb  = (blockIdx.x >> 2) & 1;
    const int b   = blockIdx.x >> 3;

    if (tid < 256) {
        int h = tid >> 4, w = tid & 15;
        float e[4], mx = -1e30f;
        #pragma unroll
        for (int r = 0; r < 4; ++r) { e[r] = cwh[h * 4 + r] + cww[w * 4 + r]; mx = fmaxf(mx, e[r]); }
        float se = 0.f;
        #pragma unroll
        for (int r = 0; r < 4; ++r) { e[r] = expf(e[r] - mx); se += e[r]; }
        float inv = 1.f / se;
        #pragma unroll
        for (int r = 0; r < 4; ++r) cwt[tid][r] = e[r] * inv;
    }

    constexpr int NCHA = NR * WT * CG;  // 2160
    for (int ch = tid; ch < NCHA; ch += 512) {
        int r    = ch / (WT * CG);
        int rem  = ch % (WT * CG);
        int wp   = rem / CG, slot = rem % CG;
        int gg_ = slot ^ ((wp >> 1) & 3);
        int h = mb * 8 + r - 1;
        int w = wp - 1;
        s16x8 val = {};
        if (h >= 0 && h < 16 && w >= 0 && w < 16)
            val = *(const s16x8*)(xin + (((size_t)(b * 16 + h) * 16 + w) * CI + gg_ * 8));
        *(s16x8*)(sm + ch * 16) = val;
    }
    __syncthreads();

    f32x4 acc[4][2];
    #pragma unroll
    for (int i = 0; i < 4; ++i)
        #pragma unroll
        for (int j = 0; j < 2; ++j) acc[i][j] = (f32x4){0.f, 0.f, 0.f, 0.f};

    const int tbase = ((cbk * 2 + g) * 2 + rp);
    for (int s = 0; s < 9; ++s) {
        const int dy = s / 3, dx = s % 3;
        s16x8 bf[2][3];
        #pragma unroll
        for (int j = 0; j < 2; ++j)
            #pragma unroll
            for (int kk = 0; kk < 3; ++kk) {
                int fidx = ((s * 32 + tbase * 2 + j) * 3 + kk) * 512 + lane * 8;
                bf[j][kk] = *(const s16x8*)(wpk3 + fidx);
            }
        #pragma unroll
        for (int kk = 0; kk < 3; ++kk) {
            const int gg = kk * 4 + quad;
            s16x8 a[4];
            #pragma unroll
            for (int mi = 0; mi < 4; ++mi) {
                int mf = wm * 4 + mi;
                int r  = mf + dy;
                int wp = col + dx;
                int addr = (r * WT + wp) * (CI * 2) + ((gg ^ ((wp >> 1) & 3)) << 4);
                a[mi] = *(const s16x8*)(sm + addr);
            }
            #pragma unroll
            for (int mi = 0; mi < 4; ++mi)
                #pragma unroll
                for (int j = 0; j < 2; ++j)
                    acc[mi][j] = __builtin_amdgcn_mfma_f32_16x16x32_bf16(
                        a[mi], bf[j][kk], acc[mi][j], 0, 0, 0);
        }
    }
    __syncthreads();

    float* ldo = (float*)sm;   // [2][128][33]
    {
        const int c_lo = g * 16 + col;
        const int cg   = cbk * 32 + c_lo;
        float bbA = bbias[(rp * 2 + 0) * 128 + cg];
        float bbB = bbias[(rp * 2 + 1) * 128 + cg];
        #pragma unroll
        for (int mi = 0; mi < 4; ++mi) {
            int mf = wm * 4 + mi;
            #pragma unroll
            for (int rg = 0; rg < 4; ++rg) {
                int hwl = mf * 16 + quad * 4 + rg;
                int hwg = mb * 128 + hwl;
                float o = cwt[hwg][rp * 2]     * (acc[mi][0][rg] + bbA)
                        + cwt[hwg][rp * 2 + 1] * (acc[mi][1][rg] + bbB);
                ldo[(rp * 128 + hwl) * 33 + c_lo] = o;
            }
        }
    }
    __syncthreads();
    {
        int cl = tid >> 4;
        int sg = tid & 15;
        size_t base = (size_t)b * 32768 + (cbk * 32 + cl) * 256 + mb * 128 + sg * 8;
        s16x8 v;
        #pragma unroll
        for (int i = 0; i < 8; ++i) {
            int hw = sg * 8 + i;
            float o = ldo[hw * 33 + cl] + ldo[(128 + hw) * 33 + cl];
            v[i] = (short)f2bf(fmaxf(o, 0.f));
        }
        *(s16x8*)(actB + base) = v;
    }
}

// ---------------------------------------------------------------------------
// fc1 MFMA GEMM (R10-proven): both operands LDS-staged, T14 reg prefetch,
// XCD-aware ks mapping, K-split 64.
// ---------------------------------------------------------------------------
__global__ __launch_bounds__(256) void fc1_lds(
    const unsigned short* __restrict__ actB, // (64, 32768) bf16
    const float* __restrict__ w,             // (512, 32768) f32
    float* __restrict__ partial)             // (64, 512, 64)
{
    __shared__ __align__(16) unsigned short Wl[64 * 256];
    __shared__ __align__(16) unsigned short Al[64 * 256];

    const int tid = threadIdx.x;
    const int wave = tid >> 6, lane = tid & 63;
    const int quad = lane >> 4, col = lane & 15;
    const int wm = wave & 1, wn = wave >> 1;
    const int xcd  = blockIdx.x & 7;
    const int slot = blockIdx.x >> 3;
    const int ks = xcd * 8 + (slot >> 3);
    const int jt = slot & 7;

    const int rt  = tid >> 2;
    const int seg = tid & 3;

    const float* wsrc = w + (size_t)(jt * 64 + rt) * 32768 + ks * 512 + seg * 64;
    const unsigned short* asrc = actB + (size_t)rt * 32768 + ks * 512 + seg * 64;

    f32x4 acc[2][2];
    #pragma unroll
    for (int i = 0; i < 2; ++i)
        #pragma unroll
        for (int j = 0; j < 2; ++j) acc[i][j] = (f32x4){0.f, 0.f, 0.f, 0.f};

    float4 pw0[8], pw1[8]; s16x8 pa[8];
    #pragma unroll
    for (int u = 0; u < 8; ++u) {
        pw0[u] = *(const float4*)(wsrc + u * 8);
        pw1[u] = *(const float4*)(wsrc + u * 8 + 4);
        pa[u]  = *(const s16x8*)(asrc + u * 8);
    }

    #pragma unroll
    for (int c = 0; c < 2; ++c) {
        #pragma unroll
        for (int u = 0; u < 8; ++u) {
            s16x8 v;
            v[0] = (short)f2bf(pw0[u].x); v[1] = (short)f2bf(pw0[u].y);
            v[2] = (short)f2bf(pw0[u].z); v[3] = (short)f2bf(pw0[u].w);
            v[4] = (short)f2bf(pw1[u].x); v[5] = (short)f2bf(pw1[u].y);
            v[6] = (short)f2bf(pw1[u].z); v[7] = (short)f2bf(pw1[u].w);
            int phys = (seg * 8 + u) ^ (rt & 7);
            *(s16x8*)(Wl + rt * 256 + phys * 8) = v;
            *(s16x8*)(Al + rt * 256 + phys * 8) = pa[u];
        }
        __syncthreads();
        if (c == 0) {
            #pragma unroll
            for (int u = 0; u < 8; ++u) {
                pw0[u] = *(const float4*)(wsrc + 256 + u * 8);
                pw1[u] = *(const float4*)(wsrc + 256 + u * 8 + 4);
                pa[u]  = *(const s16x8*)(asrc + 256 + u * 8);
            }
        }
        #pragma unroll
        for (int kk = 0; kk < 8; ++kk) {
            const int gg = kk * 4 + quad;
            s16x8 a[2], bb[2];
            #pragma unroll
            for (int mf = 0; mf < 2; ++mf) {
                int j_l = wm * 32 + mf * 16 + col;
                a[mf] = *(const s16x8*)(Wl + j_l * 256 + ((gg ^ (j_l & 7)) << 3));
            }
            #pragma unroll
            for (int bg = 0; bg < 2; ++bg) {
                int b_l = wn * 32 + bg * 16 + col;
                bb[bg] = *(const s16x8*)(Al + b_l * 256 + ((gg ^ (b_l & 7)) << 3));
            }
            #pragma unroll
            for (int mf = 0; mf < 2; ++mf)
                #pragma unroll
                for (int bg = 0; bg < 2; ++bg)
                    acc[mf][bg] = __builtin_amdgcn_mfma_f32_16x16x32_bf16(
                        a[mf], bb[bg], acc[mf][bg], 0, 0, 0);
        }
        __syncthreads();
    }
    #pragma unroll
    for (int mf = 0; mf < 2; ++mf)
        #pragma unroll
        for (int bg = 0; bg < 2; ++bg)
            #pragma unroll
            for (int r = 0; r < 4; ++r) {
                int j = jt * 64 + wm * 32 + mf * 16 + quad * 4 + r;
                int b = wn * 32 + bg * 16 + col;
                partial[((size_t)ks * 512 + j) * 64 + b] = acc[mf][bg][r];
            }
}

__global__ __launch_bounds__(256) void fc1_reduce4(
    const float* __restrict__ partial, const float* __restrict__ bias,
    float* __restrict__ out)             // (64,512)
{
    int idx = blockIdx.x * 256 + threadIdx.x;
    int b = idx & 63, j = idx >> 6;
    float a = bias[j];
    #pragma unroll 8
    for (int ks = 0; ks < 64; ++ks)
        a += partial[((size_t)ks * 512 + j) * 64 + b];
    out[b * 512 + j] = fmaxf(a, 0.f);
}

__global__ __launch_bounds__(256) void fc2_kernel(
    const float* __restrict__ x,    // (64, 512)
    const float* __restrict__ w,    // (10, 512)
    const float* __restrict__ bias,
    float* __restrict__ out)        // (64, 10)
{
    int idx = blockIdx.x * 256 + threadIdx.x;
    if (idx >= 640) return;
    int n = idx % 10, b = idx / 10;
    float a = bias[n];
    const float* xr = x + b * 512;
    const float* wr = w + n * 512;
    for (int j = 0; j < 512; ++j) a = fmaf(xr[j], wr[j], a);
    out[idx] = a;
}

// ---------------------------------------------------------------------------
extern "C" void kernel_launch(void* const* d_in, const int* in_sizes, int n_in,
                              void* d_out, int out_size, void* d_ws, size_t ws_size,
                              hipStream_t stream) {
    const float* x   = (const float*)d_in[0];
    const float* c1w = (const float*)d_in[1];  const float* c1b = (const float*)d_in[2];
    const float* b1g = (const float*)d_in[3];  const float* b1b = (const float*)d_in[4];
    const float* b1m = (const float*)d_in[5];  const float* b1v = (const float*)d_in[6];
    const float* c2w = (const float*)d_in[7];  const float* c2b = (const float*)d_in[8];
    const float* b2g = (const float*)d_in[9];  const float* b2b = (const float*)d_in[10];
    const float* b2m = (const float*)d_in[11]; const float* b2v = (const float*)d_in[12];
    const float* c3w = (const float*)d_in[13]; const float* c3b = (const float*)d_in[14];
    const float* b3g = (const float*)d_in[15]; const float* b3b = (const float*)d_in[16];
    const float* b3m = (const float*)d_in[17]; const float* b3v = (const float*)d_in[18];
    const float* bw  = (const float*)d_in[19]; const float* bb  = (const float*)d_in[20];
    const float* cwh = (const float*)d_in[21]; const float* cww = (const float*)d_in[22];
    const float* f1w = (const float*)d_in[23]; const float* f1b = (const float*)d_in[24];
    const float* f2w = (const float*)d_in[25]; const float* f2b = (const float*)d_in[26];
    float* out = (float*)d_out;

    char* ws = (char*)d_ws;
    unsigned short* act1 = (unsigned short*)(ws + 0);           // [0,16M)
    unsigned short* act2 = (unsigned short*)(ws + 16777216);    // [16M,24M)
    unsigned short* act3 = (unsigned short*)(ws + 0);           // [0,3M)   (act1 dead)
    unsigned short* actB = (unsigned short*)(ws + 4194304);     // [4M,8M)
    float*          part = (float*)(ws + 8388608);              // [8M,16M) 64x512x64
    float*          fc1o = (float*)(ws + 0);                    // [0,128K) (act3 dead)
    unsigned short* wp2S = (unsigned short*)(ws + 25165824);    //  36,864 B
    unsigned short* wp3F = (unsigned short*)(ws + 25202688);    // 110,592 B
    unsigned short* wpL3 = (unsigned short*)(ws + 25313280);    // 884,736 B
    float*          wf1  = (float*)(ws + 26198016);             //   1,280 B

    repack_w<<<2018, 256, 0, stream>>>(c2w, c3w, bw, c1w, c1b, b1g, b1b, b1m, b1v,
                                       wp2S, wp3F, wpL3, wf1);

    conv1_s<<<1024, 256, 0, stream>>>(x, wf1, act1);

    conv2_mfma<<<2048, 256, 0, stream>>>(act1, wp2S, c2b, b2g, b2b, b2m, b2v, act2);

    conv3_mfma<<<1024, 256, 0, stream>>>(act2, wp3F, c3b, b3g, b3b, b3m, b3v, act3);

    lrlc_mfma4<<<512, 512, 0, stream>>>(act3, wp3F == 0 ? 0 : wpL3, bb, cwh, cww, actB);

    fc1_lds<<<512, 256, 0, stream>>>(actB, f1w, part);
    fc1_reduce4<<<128, 256, 0, stream>>>(part, f1b, fc1o);
    fc2_kernel<<<3, 256, 0, stream>>>(fc1o, f2w, f2b, out);
}

// Round 15
// 101.066 us; speedup vs baseline: 1.2949x; 1.1706x over previous
//
#include <hip/hip_runtime.h>
#include <hip/hip_bf16.h>

#define EPS 1e-5f

typedef short s16x8 __attribute__((ext_vector_type(8)));
typedef float f32x4 __attribute__((ext_vector_type(4)));

__device__ __forceinline__ unsigned short f2bf(float f) {
    unsigned u = __float_as_uint(f);
    u += 0x7fffu + ((u >> 16) & 1u);
    return (unsigned short)(u >> 16);
}

// ---------------------------------------------------------------------------
// Repack. wp2S: conv2 B LDS-image. wp3F: conv3 B frag-order. wpL3: LRLC
// frag-order. wf1: conv1 BN-folded [32][10].
// ---------------------------------------------------------------------------
__global__ __launch_bounds__(256) void repack_w(
    const float* __restrict__ c2w, const float* __restrict__ c3w,
    const float* __restrict__ bw,
    const float* __restrict__ c1w, const float* __restrict__ c1b,
    const float* __restrict__ b1g, const float* __restrict__ b1b,
    const float* __restrict__ b1m, const float* __restrict__ b1v,
    unsigned short* __restrict__ wp2S, unsigned short* __restrict__ wp3F,
    unsigned short* __restrict__ wpL3, float* __restrict__ wf1)
{
    int idx = blockIdx.x * 256 + threadIdx.x;
    if (idx < 18432) {                       // conv2 staged image: 2304 ch x 8
        int ch = idx >> 3, e = idx & 7;
        int co = ch / 36, rem = ch % 36;
        int s = rem >> 2, slot = rem & 3;
        int g = slot ^ ((co >> 1) & 3);
        int ci = g * 8 + e;
        wp2S[idx] = f2bf(c2w[(co * 32 + ci) * 9 + s]);
    } else if (idx < 73728) {                // conv3 frag-order: 108 frags x 512
        int i = idx - 18432;
        int e    = i & 7;
        int lane = (i >> 3) & 63;
        int f    = i >> 9;            // (s*2+kk)*6 + cg
        int cg   = f % 6;
        int t2   = f / 6;
        int kk   = t2 & 1;
        int s    = t2 >> 1;
        int col = lane & 15, quad = lane >> 4;
        int co = cg * 16 + col;
        int ci = (kk * 4 + quad) * 8 + e;
        wp3F[i] = f2bf(c3w[(co * 64 + ci) * 9 + s]);
    } else if (idx < 516096) {               // lrlc frag-order: 442368 elems
        int i = idx - 73728;
        int e    = i & 7;
        int lane = (i >> 3) & 63;
        int fk   = i >> 9;            // t*3 + kk
        int kk   = fk % 3;
        int t    = fk / 3;            // = (((s*4+cbk)*2+g)*2+rp)*2+j
        int j    = t & 1;
        int rp   = (t >> 1) & 1;
        int g    = (t >> 2) & 1;
        int cbk  = (t >> 3) & 3;
        int s    = t >> 5;
        int col = lane & 15, quad = lane >> 4;
        int cog = (rp * 2 + j) * 128 + cbk * 32 + g * 16 + col;
        int ci  = (kk * 4 + quad) * 8 + e;
        wpL3[i] = f2bf(bw[(cog * 96 + ci) * 9 + s]);
    } else if (idx < 516416) {               // conv1 folded: 32 x 10
        int i = idx - 516096;
        int co = i / 10, k = i % 10;
        float scl = b1g[co] * rsqrtf(b1v[co] + EPS);
        wf1[i] = (k < 9) ? c1w[co * 9 + k] * scl
                         : (c1b[co] - b1m[co]) * scl + b1b[co];
    }
}

// ---------------------------------------------------------------------------
// conv1 hybrid: block = (b, ph); 4-row x-strip staged once in padded LDS;
// wave = co-chunk of 8 (80 wave-uniform folded weights -> SGPR-hoistable);
// thread = pw, 4x4 patch from LDS reused over 8 channels (288 FMA : 8 LDS).
// ---------------------------------------------------------------------------
__global__ __launch_bounds__(256) void conv1_h(
    const float* __restrict__ x,      // (64,1,128,128)
    const float* __restrict__ wf1,    // (32,10) folded
    unsigned short* __restrict__ out) // (64,64,64,32) NHWC bf16
{
    __shared__ float xs[4][132];

    const int tid = threadIdx.x;
    const int b = blockIdx.x >> 6, ph = blockIdx.x & 63;

    for (int i = tid; i < 4 * 132; i += 256) ((float*)xs)[i] = 0.f;
    __syncthreads();
    const int row0 = 2 * ph - 1;
    for (int i = tid; i < 4 * 128; i += 256) {
        int r = i >> 7, c = i & 127;
        int gr = row0 + r;
        if (gr >= 0 && gr < 128)
            xs[r][c + 1] = x[(size_t)b * 16384 + gr * 128 + c];
    }
    __syncthreads();

    const int pw = tid & 63, wavei = tid >> 6;
    float pr[4][4];
    #pragma unroll
    for (int rr = 0; rr < 4; ++rr) {
        float2 u0 = *(const float2*)&xs[rr][2 * pw];
        float2 u1 = *(const float2*)&xs[rr][2 * pw + 2];
        pr[rr][0] = u0.x; pr[rr][1] = u0.y; pr[rr][2] = u1.x; pr[rr][3] = u1.y;
    }

    const float* wb = wf1 + wavei * 80;   // wave-uniform base
    s16x8 res;
    #pragma unroll
    for (int c8 = 0; c8 < 8; ++c8) {
        const float* wv = wb + c8 * 10;
        float a00 = 0.f, a01 = 0.f, a10 = 0.f, a11 = 0.f;
        #pragma unroll
        for (int ky = 0; ky < 3; ++ky)
            #pragma unroll
            for (int kx = 0; kx < 3; ++kx) {
                float wk = wv[ky * 3 + kx];
                a00 = fmaf(wk, pr[ky][kx],         a00);
                a01 = fmaf(wk, pr[ky][kx + 1],     a01);
                a10 = fmaf(wk, pr[ky + 1][kx],     a10);
                a11 = fmaf(wk, pr[ky + 1][kx + 1], a11);
            }
        float o = fmaxf(fmaxf(fmaxf(a00, a01), fmaxf(a10, a11)) + wv[9], 0.f);
        res[c8] = (short)f2bf(o);
    }
    *(s16x8*)(out + (((size_t)(b * 64 + ph)) * 64 + pw) * 32 + wavei * 8) = res;
}

// ---------------------------------------------------------------------------
// conv2: implicit-GEMM + BN + ReLU + pool, all-shift B via linear copy.
// ---------------------------------------------------------------------------
__global__ __launch_bounds__(256) void conv2_mfma(
    const unsigned short* __restrict__ xin,  // (64,64,64,32)
    const unsigned short* __restrict__ wp2S, // staged image 18432
    const float* __restrict__ cbv, const float* __restrict__ gg,
    const float* __restrict__ bnb, const float* __restrict__ mm,
    const float* __restrict__ vv,
    unsigned short* __restrict__ out)        // (64,32,32,64)
{
    constexpr int CI = 32, CO = 64, W = 64, WT = 66, CG = 4;
    constexpr int ASZ = 4 * WT * CI * 2;     // 16896
    constexpr int BSZ = 9 * CO * CI * 2;     // 36864
    constexpr int PH2 = 32, HPX = 4;

    __shared__ __align__(16) unsigned char sm[ASZ + BSZ];

    const int tid = threadIdx.x;
    const int wave = tid >> 6, lane = tid & 63;
    const int quad = lane >> 4, col = lane & 15;
    const int wm = wave;

    const int xcd  = blockIdx.x & 7;
    const int slot = blockIdx.x >> 3;
    const int hp = xcd * HPX + (slot % HPX);
    const int b  = slot / HPX;

    constexpr int NCHA = 4 * WT * CG;
    for (int ch = tid; ch < NCHA; ch += 256) {
        int r    = ch / (WT * CG);
        int rem  = ch % (WT * CG);
        int wp   = rem / CG;
        int slot_ = rem % CG;
        int g = slot_ ^ ((wp >> 1) & 3);
        int h = hp * 2 - 1 + r;
        int w = wp - 1;
        s16x8 val = {};
        if (h >= 0 && h < W && w >= 0 && w < W)
            val = *(const s16x8*)(xin + (((size_t)(b * W + h) * W + w) * CI + g * 8));
        *(s16x8*)(sm + ch * 16) = val;
    }
    for (int ch = tid; ch < 2304; ch += 256)
        *(s16x8*)(sm + ASZ + ch * 16) = *(const s16x8*)(wp2S + ch * 8);
    __syncthreads();

    f32x4 acc[2][4];
    #pragma unroll
    for (int i = 0; i < 2; ++i)
        #pragma unroll
        for (int j = 0; j < 4; ++j) acc[i][j] = (f32x4){0.f, 0.f, 0.f, 0.f};

    #pragma unroll
    for (int s = 0; s < 9; ++s) {
        const int dy = s / 3, dx = s % 3;
        const int g = quad;
        s16x8 a[2];
        #pragma unroll
        for (int mi = 0; mi < 2; ++mi) {
            int wp = wm * 16 + col + dx;
            int r  = mi + dy;
            int addr = (r * WT + wp) * (CI * 2) + ((g ^ ((wp >> 1) & 3)) << 4);
            a[mi] = *(const s16x8*)(sm + addr);
        }
        #pragma unroll
        for (int nf = 0; nf < 4; ++nf) {
            int co_l = nf * 16 + col;
            int row = co_l * 9 + s;
            int addr = ASZ + row * (CI * 2) + ((g ^ ((co_l >> 1) & 3)) << 4);
            s16x8 bf = *(const s16x8*)(sm + addr);
            acc[0][nf] = __builtin_amdgcn_mfma_f32_16x16x32_bf16(a[0], bf, acc[0][nf], 0, 0, 0);
            acc[1][nf] = __builtin_amdgcn_mfma_f32_16x16x32_bf16(a[1], bf, acc[1][nf], 0, 0, 0);
        }
    }

    #pragma unroll
    for (int nf = 0; nf < 4; ++nf) {
        int co = nf * 16 + col;
        float scl = gg[co] * rsqrtf(vv[co] + EPS);
        float sh  = (cbv[co] - mm[co]) * scl + bnb[co];
        #pragma unroll
        for (int pr = 0; pr < 2; ++pr) {
            float y0 = fmaf(acc[0][nf][2 * pr],     scl, sh);
            float y1 = fmaf(acc[0][nf][2 * pr + 1], scl, sh);
            float y2 = fmaf(acc[1][nf][2 * pr],     scl, sh);
            float y3 = fmaf(acc[1][nf][2 * pr + 1], scl, sh);
            float o = fmaxf(fmaxf(fmaxf(y0, y1), fmaxf(y2, y3)), 0.f);
            int pw = wm * 8 + quad * 2 + pr;
            out[((size_t)(b * PH2 + hp) * PH2 + pw) * CO + co] = f2bf(o);
        }
    }
}

// ---------------------------------------------------------------------------
// conv3 v2: B per-wave from fragment-ordered wp3F (no B-LDS, 1 barrier).
// ---------------------------------------------------------------------------
__global__ __launch_bounds__(256) void conv3_mfma(
    const unsigned short* __restrict__ xin,  // (64,32,32,64)
    const unsigned short* __restrict__ wp3F, // frag-ordered 55296
    const float* __restrict__ cbv, const float* __restrict__ gg,
    const float* __restrict__ bnb, const float* __restrict__ mm,
    const float* __restrict__ vv,
    unsigned short* __restrict__ out)        // (64,16,16,96)
{
    constexpr int CI = 64, CO = 96, W = 32, WT = 34, CG = 8;
    constexpr int ASZ = 4 * WT * CI * 2;     // 17408
    constexpr int PH2 = 16, HPX = 2;

    __shared__ __align__(16) unsigned char sm[ASZ];

    const int tid = threadIdx.x;
    const int wave = tid >> 6, lane = tid & 63;
    const int quad = lane >> 4, col = lane & 15;
    const int wm = wave & 1, wn = wave >> 1;

    const int xcd  = blockIdx.x & 7;
    const int slot = blockIdx.x >> 3;
    const int hp = xcd * HPX + (slot % HPX);
    const int b  = slot / HPX;

    constexpr int NCHA = 4 * WT * CG;   // 1088
    for (int ch = tid; ch < NCHA; ch += 256) {
        int r    = ch / (WT * CG);
        int rem  = ch % (WT * CG);
        int wp   = rem / CG;
        int slot_ = rem % CG;
        int g = slot_ ^ (wp & 7);
        int h = hp * 2 - 1 + r;
        int w = wp - 1;
        s16x8 val = {};
        if (h >= 0 && h < W && w >= 0 && w < W)
            val = *(const s16x8*)(xin + (((size_t)(b * W + h) * W + w) * CI + g * 8));
        *(s16x8*)(sm + ch * 16) = val;
    }
    __syncthreads();

    f32x4 acc[2][3];
    #pragma unroll
    for (int i = 0; i < 2; ++i)
        #pragma unroll
        for (int j = 0; j < 3; ++j) acc[i][j] = (f32x4){0.f, 0.f, 0.f, 0.f};

    for (int s = 0; s < 9; ++s) {
        const int dy = s / 3, dx = s % 3;
        s16x8 bf[3][2];
        #pragma unroll
        for (int nf = 0; nf < 3; ++nf)
            #pragma unroll
            for (int kk = 0; kk < 2; ++kk) {
                int fidx = (((s * 2 + kk) * 6) + wn * 3 + nf) * 512 + lane * 8;
                bf[nf][kk] = *(const s16x8*)(wp3F + fidx);
            }
        #pragma unroll
        for (int kk = 0; kk < 2; ++kk) {
            const int g = kk * 4 + quad;
            s16x8 a[2];
            #pragma unroll
            for (int mi = 0; mi < 2; ++mi) {
                int wp = wm * 16 + col + dx;
                int r  = mi + dy;
                int addr = (r * WT + wp) * (CI * 2) + ((g ^ (wp & 7)) << 4);
                a[mi] = *(const s16x8*)(sm + addr);
            }
            #pragma unroll
            for (int nf = 0; nf < 3; ++nf) {
                acc[0][nf] = __builtin_amdgcn_mfma_f32_16x16x32_bf16(a[0], bf[nf][kk], acc[0][nf], 0, 0, 0);
                acc[1][nf] = __builtin_amdgcn_mfma_f32_16x16x32_bf16(a[1], bf[nf][kk], acc[1][nf], 0, 0, 0);
            }
        }
    }

    #pragma unroll
    for (int nf = 0; nf < 3; ++nf) {
        int co = (wn * 3 + nf) * 16 + col;
        float scl = gg[co] * rsqrtf(vv[co] + EPS);
        float sh  = (cbv[co] - mm[co]) * scl + bnb[co];
        #pragma unroll
        for (int pr = 0; pr < 2; ++pr) {
            float y0 = fmaf(acc[0][nf][2 * pr],     scl, sh);
            float y1 = fmaf(acc[0][nf][2 * pr + 1], scl, sh);
            float y2 = fmaf(acc[1][nf][2 * pr],     scl, sh);
            float y3 = fmaf(acc[1][nf][2 * pr + 1], scl, sh);
            float o = fmaxf(fmaxf(fmaxf(y0, y1), fmaxf(y2, y3)), 0.f);
            int pw = wm * 8 + quad * 2 + pr;
            out[((size_t)(b * PH2 + hp) * PH2 + pw) * CO + co] = f2bf(o);
        }
    }
}

// ---------------------------------------------------------------------------
// LRLC v4: B per-wave from fragment-ordered wpL3 (no B-LDS, 3 barriers).
// ---------------------------------------------------------------------------
__global__ __launch_bounds__(512) void lrlc_mfma4(
    const unsigned short* __restrict__ xin,  // (64,16,16,96) bf16
    const unsigned short* __restrict__ wpk3, // frag-ordered (442368)
    const float* __restrict__ bbias,         // (4,128)
    const float* __restrict__ cwh, const float* __restrict__ cww,
    unsigned short* __restrict__ actB)       // (64, 32768) bf16
{
    constexpr int CI = 96, WT = 18, NR = 10, CG = 12;
    constexpr int ASZ = NR * WT * CI * 2;    // 34560 B
    __shared__ __align__(16) unsigned char sm[ASZ];
    __shared__ float cwt[256][4];

    const int tid = threadIdx.x;
    const int wave = tid >> 6, lane = tid & 63;
    const int quad = lane >> 4, col = lane & 15;
    const int wm = wave & 1;
    const int g  = (wave >> 1) & 1;
    const int rp = wave >> 2;

    const int cbk = blockIdx.x & 3;
    const int mb  = (blockIdx.x >> 2) & 1;
    const int b   = blockIdx.x >> 3;

    if (tid < 256) {
        int h = tid >> 4, w = tid & 15;
        float e[4], mx = -1e30f;
        #pragma unroll
        for (int r = 0; r < 4; ++r) { e[r] = cwh[h * 4 + r] + cww[w * 4 + r]; mx = fmaxf(mx, e[r]); }
        float se = 0.f;
        #pragma unroll
        for (int r = 0; r < 4; ++r) { e[r] = expf(e[r] - mx); se += e[r]; }
        float inv = 1.f / se;
        #pragma unroll
        for (int r = 0; r < 4; ++r) cwt[tid][r] = e[r] * inv;
    }

    constexpr int NCHA = NR * WT * CG;  // 2160
    for (int ch = tid; ch < NCHA; ch += 512) {
        int r    = ch / (WT * CG);
        int rem  = ch % (WT * CG);
        int wp   = rem / CG, slot = rem % CG;
        int gg_ = slot ^ ((wp >> 1) & 3);
        int h = mb * 8 + r - 1;
        int w = wp - 1;
        s16x8 val = {};
        if (h >= 0 && h < 16 && w >= 0 && w < 16)
            val = *(const s16x8*)(xin + (((size_t)(b * 16 + h) * 16 + w) * CI + gg_ * 8));
        *(s16x8*)(sm + ch * 16) = val;
    }
    __syncthreads();

    f32x4 acc[4][2];
    #pragma unroll
    for (int i = 0; i < 4; ++i)
        #pragma unroll
        for (int j = 0; j < 2; ++j) acc[i][j] = (f32x4){0.f, 0.f, 0.f, 0.f};

    const int tbase = ((cbk * 2 + g) * 2 + rp);
    for (int s = 0; s < 9; ++s) {
        const int dy = s / 3, dx = s % 3;
        s16x8 bf[2][3];
        #pragma unroll
        for (int j = 0; j < 2; ++j)
            #pragma unroll
            for (int kk = 0; kk < 3; ++kk) {
                int fidx = ((s * 32 + tbase * 2 + j) * 3 + kk) * 512 + lane * 8;
                bf[j][kk] = *(const s16x8*)(wpk3 + fidx);
            }
        #pragma unroll
        for (int kk = 0; kk < 3; ++kk) {
            const int gg = kk * 4 + quad;
            s16x8 a[4];
            #pragma unroll
            for (int mi = 0; mi < 4; ++mi) {
                int mf = wm * 4 + mi;
                int r  = mf + dy;
                int wp = col + dx;
                int addr = (r * WT + wp) * (CI * 2) + ((gg ^ ((wp >> 1) & 3)) << 4);
                a[mi] = *(const s16x8*)(sm + addr);
            }
            #pragma unroll
            for (int mi = 0; mi < 4; ++mi)
                #pragma unroll
                for (int j = 0; j < 2; ++j)
                    acc[mi][j] = __builtin_amdgcn_mfma_f32_16x16x32_bf16(
                        a[mi], bf[j][kk], acc[mi][j], 0, 0, 0);
        }
    }
    __syncthreads();

    float* ldo = (float*)sm;   // [2][128][33]
    {
        const int c_lo = g * 16 + col;
        const int cg   = cbk * 32 + c_lo;
        float bbA = bbias[(rp * 2 + 0) * 128 + cg];
        float bbB = bbias[(rp * 2 + 1) * 128 + cg];
        #pragma unroll
        for (int mi = 0; mi < 4; ++mi) {
            int mf = wm * 4 + mi;
            #pragma unroll
            for (int rg = 0; rg < 4; ++rg) {
                int hwl = mf * 16 + quad * 4 + rg;
                int hwg = mb * 128 + hwl;
                float o = cwt[hwg][rp * 2]     * (acc[mi][0][rg] + bbA)
                        + cwt[hwg][rp * 2 + 1] * (acc[mi][1][rg] + bbB);
                ldo[(rp * 128 + hwl) * 33 + c_lo] = o;
            }
        }
    }
    __syncthreads();
    {
        int cl = tid >> 4;
        int sg = tid & 15;
        size_t base = (size_t)b * 32768 + (cbk * 32 + cl) * 256 + mb * 128 + sg * 8;
        s16x8 v;
        #pragma unroll
        for (int i = 0; i < 8; ++i) {
            int hw = sg * 8 + i;
            float o = ldo[hw * 33 + cl] + ldo[(128 + hw) * 33 + cl];
            v[i] = (short)f2bf(fmaxf(o, 0.f));
        }
        *(s16x8*)(actB + base) = v;
    }
}

// ---------------------------------------------------------------------------
// fc1 MFMA GEMM (R10-proven): both operands LDS-staged, T14 reg prefetch,
// XCD-aware ks mapping, K-split 64.
// ---------------------------------------------------------------------------
__global__ __launch_bounds__(256) void fc1_lds(
    const unsigned short* __restrict__ actB, // (64, 32768) bf16
    const float* __restrict__ w,             // (512, 32768) f32
    float* __restrict__ partial)             // (64, 512, 64)
{
    __shared__ __align__(16) unsigned short Wl[64 * 256];
    __shared__ __align__(16) unsigned short Al[64 * 256];

    const int tid = threadIdx.x;
    const int wave = tid >> 6, lane = tid & 63;
    const int quad = lane >> 4, col = lane & 15;
    const int wm = wave & 1, wn = wave >> 1;
    const int xcd  = blockIdx.x & 7;
    const int slot = blockIdx.x >> 3;
    const int ks = xcd * 8 + (slot >> 3);
    const int jt = slot & 7;

    const int rt  = tid >> 2;
    const int seg = tid & 3;

    const float* wsrc = w + (size_t)(jt * 64 + rt) * 32768 + ks * 512 + seg * 64;
    const unsigned short* asrc = actB + (size_t)rt * 32768 + ks * 512 + seg * 64;

    f32x4 acc[2][2];
    #pragma unroll
    for (int i = 0; i < 2; ++i)
        #pragma unroll
        for (int j = 0; j < 2; ++j) acc[i][j] = (f32x4){0.f, 0.f, 0.f, 0.f};

    float4 pw0[8], pw1[8]; s16x8 pa[8];
    #pragma unroll
    for (int u = 0; u < 8; ++u) {
        pw0[u] = *(const float4*)(wsrc + u * 8);
        pw1[u] = *(const float4*)(wsrc + u * 8 + 4);
        pa[u]  = *(const s16x8*)(asrc + u * 8);
    }

    #pragma unroll
    for (int c = 0; c < 2; ++c) {
        #pragma unroll
        for (int u = 0; u < 8; ++u) {
            s16x8 v;
            v[0] = (short)f2bf(pw0[u].x); v[1] = (short)f2bf(pw0[u].y);
            v[2] = (short)f2bf(pw0[u].z); v[3] = (short)f2bf(pw0[u].w);
            v[4] = (short)f2bf(pw1[u].x); v[5] = (short)f2bf(pw1[u].y);
            v[6] = (short)f2bf(pw1[u].z); v[7] = (short)f2bf(pw1[u].w);
            int phys = (seg * 8 + u) ^ (rt & 7);
            *(s16x8*)(Wl + rt * 256 + phys * 8) = v;
            *(s16x8*)(Al + rt * 256 + phys * 8) = pa[u];
        }
        __syncthreads();
        if (c == 0) {
            #pragma unroll
            for (int u = 0; u < 8; ++u) {
                pw0[u] = *(const float4*)(wsrc + 256 + u * 8);
                pw1[u] = *(const float4*)(wsrc + 256 + u * 8 + 4);
                pa[u]  = *(const s16x8*)(asrc + 256 + u * 8);
            }
        }
        #pragma unroll
        for (int kk = 0; kk < 8; ++kk) {
            const int gg = kk * 4 + quad;
            s16x8 a[2], bb[2];
            #pragma unroll
            for (int mf = 0; mf < 2; ++mf) {
                int j_l = wm * 32 + mf * 16 + col;
                a[mf] = *(const s16x8*)(Wl + j_l * 256 + ((gg ^ (j_l & 7)) << 3));
            }
            #pragma unroll
            for (int bg = 0; bg < 2; ++bg) {
                int b_l = wn * 32 + bg * 16 + col;
                bb[bg] = *(const s16x8*)(Al + b_l * 256 + ((gg ^ (b_l & 7)) << 3));
            }
            #pragma unroll
            for (int mf = 0; mf < 2; ++mf)
                #pragma unroll
                for (int bg = 0; bg < 2; ++bg)
                    acc[mf][bg] = __builtin_amdgcn_mfma_f32_16x16x32_bf16(
                        a[mf], bb[bg], acc[mf][bg], 0, 0, 0);
        }
        __syncthreads();
    }
    #pragma unroll
    for (int mf = 0; mf < 2; ++mf)
        #pragma unroll
        for (int bg = 0; bg < 2; ++bg)
            #pragma unroll
            for (int r = 0; r < 4; ++r) {
                int j = jt * 64 + wm * 32 + mf * 16 + quad * 4 + r;
                int b = wn * 32 + bg * 16 + col;
                partial[((size_t)ks * 512 + j) * 64 + b] = acc[mf][bg][r];
            }
}

__global__ __launch_bounds__(256) void fc1_reduce4(
    const float* __restrict__ partial, const float* __restrict__ bias,
    float* __restrict__ out)             // (64,512)
{
    int idx = blockIdx.x * 256 + threadIdx.x;
    int b = idx & 63, j = idx >> 6;
    float a = bias[j];
    #pragma unroll 8
    for (int ks = 0; ks < 64; ++ks)
        a += partial[((size_t)ks * 512 + j) * 64 + b];
    out[b * 512 + j] = fmaxf(a, 0.f);
}

// ---------------------------------------------------------------------------
// fc2 wide: block per batch row; lane-split K with shuffle reduce.
// ---------------------------------------------------------------------------
__global__ __launch_bounds__(320) void fc2_w(
    const float* __restrict__ xin,   // (64,512)
    const float* __restrict__ w,     // (10,512)
    const float* __restrict__ bias,
    float* __restrict__ out)         // (64,10)
{
    const int b = blockIdx.x;
    const int tid = threadIdx.x;     // 0..319
    const int n = tid >> 5, l = tid & 31;
    const float* xr = xin + b * 512 + l * 16;
    const float* wr = w + n * 512 + l * 16;
    float s = 0.f;
    #pragma unroll
    for (int u = 0; u < 4; ++u) {
        float4 xv = *(const float4*)(xr + u * 4);
        float4 wv = *(const float4*)(wr + u * 4);
        s = fmaf(xv.x, wv.x, s); s = fmaf(xv.y, wv.y, s);
        s = fmaf(xv.z, wv.z, s); s = fmaf(xv.w, wv.w, s);
    }
    #pragma unroll
    for (int off = 16; off > 0; off >>= 1)
        s += __shfl_xor(s, off, 32);
    if (l == 0) out[b * 10 + n] = s + bias[n];
}

// ---------------------------------------------------------------------------
extern "C" void kernel_launch(void* const* d_in, const int* in_sizes, int n_in,
                              void* d_out, int out_size, void* d_ws, size_t ws_size,
                              hipStream_t stream) {
    const float* x   = (const float*)d_in[0];
    const float* c1w = (const float*)d_in[1];  const float* c1b = (const float*)d_in[2];
    const float* b1g = (const float*)d_in[3];  const float* b1b = (const float*)d_in[4];
    const float* b1m = (const float*)d_in[5];  const float* b1v = (const float*)d_in[6];
    const float* c2w = (const float*)d_in[7];  const float* c2b = (const float*)d_in[8];
    const float* b2g = (const float*)d_in[9];  const float* b2b = (const float*)d_in[10];
    const float* b2m = (const float*)d_in[11]; const float* b2v = (const float*)d_in[12];
    const float* c3w = (const float*)d_in[13]; const float* c3b = (const float*)d_in[14];
    const float* b3g = (const float*)d_in[15]; const float* b3b = (const float*)d_in[16];
    const float* b3m = (const float*)d_in[17]; const float* b3v = (const float*)d_in[18];
    const float* bw  = (const float*)d_in[19]; const float* bb  = (const float*)d_in[20];
    const float* cwh = (const float*)d_in[21]; const float* cww = (const float*)d_in[22];
    const float* f1w = (const float*)d_in[23]; const float* f1b = (const float*)d_in[24];
    const float* f2w = (const float*)d_in[25]; const float* f2b = (const float*)d_in[26];
    float* out = (float*)d_out;

    char* ws = (char*)d_ws;
    unsigned short* act1 = (unsigned short*)(ws + 0);           // [0,16M)
    unsigned short* act2 = (unsigned short*)(ws + 16777216);    // [16M,24M)
    unsigned short* act3 = (unsigned short*)(ws + 0);           // [0,3M)   (act1 dead)
    unsigned short* actB = (unsigned short*)(ws + 4194304);     // [4M,8M)
    float*          part = (float*)(ws + 8388608);              // [8M,16M) 64x512x64
    float*          fc1o = (float*)(ws + 0);                    // [0,128K) (act3 dead)
    unsigned short* wp2S = (unsigned short*)(ws + 25165824);    //  36,864 B
    unsigned short* wp3F = (unsigned short*)(ws + 25202688);    // 110,592 B
    unsigned short* wpL3 = (unsigned short*)(ws + 25313280);    // 884,736 B
    float*          wf1  = (float*)(ws + 26198016);             //   1,280 B

    repack_w<<<2018, 256, 0, stream>>>(c2w, c3w, bw, c1w, c1b, b1g, b1b, b1m, b1v,
                                       wp2S, wp3F, wpL3, wf1);

    conv1_h<<<4096, 256, 0, stream>>>(x, wf1, act1);

    conv2_mfma<<<2048, 256, 0, stream>>>(act1, wp2S, c2b, b2g, b2b, b2m, b2v, act2);

    conv3_mfma<<<1024, 256, 0, stream>>>(act2, wp3F, c3b, b3g, b3b, b3m, b3v, act3);

    lrlc_mfma4<<<512, 512, 0, stream>>>(act3, wpL3, bb, cwh, cww, actB);

    fc1_lds<<<512, 256, 0, stream>>>(actB, f1w, part);
    fc1_reduce4<<<128, 256, 0, stream>>>(part, f1b, fc1o);
    fc2_w<<<64, 320, 0, stream>>>(fc1o, f2w, f2b, out);
}

// Round 16
// 97.623 us; speedup vs baseline: 1.3406x; 1.0353x over previous
//
#include <hip/hip_runtime.h>
#include <hip/hip_bf16.h>

#define EPS 1e-5f

typedef short s16x8 __attribute__((ext_vector_type(8)));
typedef float f32x4 __attribute__((ext_vector_type(4)));

__device__ __forceinline__ unsigned short f2bf(float f) {
    unsigned u = __float_as_uint(f);
    u += 0x7fffu + ((u >> 16) & 1u);
    return (unsigned short)(u >> 16);
}

// ---------------------------------------------------------------------------
// Fused repack + conv1. Blocks [0,4096): conv1 (folds its own BN table into
// LDS; R12 showed the weight path is not conv1's bottleneck). Blocks >=4096:
// weight repack for conv2/conv3/lrlc (independent of conv1).
// ---------------------------------------------------------------------------
__global__ __launch_bounds__(256) void repack_conv1(
    const float* __restrict__ x,
    const float* __restrict__ c1w, const float* __restrict__ c1b,
    const float* __restrict__ b1g, const float* __restrict__ b1b,
    const float* __restrict__ b1m, const float* __restrict__ b1v,
    const float* __restrict__ c2w, const float* __restrict__ c3w,
    const float* __restrict__ bw,
    unsigned short* __restrict__ act1,
    unsigned short* __restrict__ wp2S, unsigned short* __restrict__ wp3F,
    unsigned short* __restrict__ wpL3)
{
    const int tid = threadIdx.x;
    if (blockIdx.x >= 4096) {
        int idx = (blockIdx.x - 4096) * 256 + tid;
        if (idx < 18432) {                       // conv2 staged image
            int ch = idx >> 3, e = idx & 7;
            int co = ch / 36, rem = ch % 36;
            int s = rem >> 2, slot = rem & 3;
            int g = slot ^ ((co >> 1) & 3);
            int ci = g * 8 + e;
            wp2S[idx] = f2bf(c2w[(co * 32 + ci) * 9 + s]);
        } else if (idx < 73728) {                // conv3 frag-order
            int i = idx - 18432;
            int e    = i & 7;
            int lane = (i >> 3) & 63;
            int f    = i >> 9;
            int cg   = f % 6;
            int t2   = f / 6;
            int kk   = t2 & 1;
            int s    = t2 >> 1;
            int col = lane & 15, quad = lane >> 4;
            int co = cg * 16 + col;
            int ci = (kk * 4 + quad) * 8 + e;
            wp3F[i] = f2bf(c3w[(co * 64 + ci) * 9 + s]);
        } else if (idx < 516096) {               // lrlc frag-order
            int i = idx - 73728;
            int e    = i & 7;
            int lane = (i >> 3) & 63;
            int fk   = i >> 9;
            int kk   = fk % 3;
            int t    = fk / 3;
            int j    = t & 1;
            int rp   = (t >> 1) & 1;
            int g    = (t >> 2) & 1;
            int cbk  = (t >> 3) & 3;
            int s    = t >> 5;
            int col = lane & 15, quad = lane >> 4;
            int cog = (rp * 2 + j) * 128 + cbk * 32 + g * 16 + col;
            int ci  = (kk * 4 + quad) * 8 + e;
            wpL3[i] = f2bf(bw[(cog * 96 + ci) * 9 + s]);
        }
        return;
    }

    // --- conv1 body (R15-proven hybrid) ---
    __shared__ float xs[4][132];
    __shared__ float wfs[320];

    const int bid = blockIdx.x;
    const int b = bid >> 6, ph = bid & 63;

    for (int i = tid; i < 4 * 132; i += 256) ((float*)xs)[i] = 0.f;
    for (int i = tid; i < 320; i += 256) {
        int co = i / 10, k = i % 10;
        float scl = b1g[co] * rsqrtf(b1v[co] + EPS);
        wfs[i] = (k < 9) ? c1w[co * 9 + k] * scl
                         : (c1b[co] - b1m[co]) * scl + b1b[co];
    }
    __syncthreads();
    const int row0 = 2 * ph - 1;
    for (int i = tid; i < 4 * 128; i += 256) {
        int r = i >> 7, c = i & 127;
        int gr = row0 + r;
        if (gr >= 0 && gr < 128)
            xs[r][c + 1] = x[(size_t)b * 16384 + gr * 128 + c];
    }
    __syncthreads();

    const int pw = tid & 63, wavei = tid >> 6;
    float pr[4][4];
    #pragma unroll
    for (int rr = 0; rr < 4; ++rr) {
        float2 u0 = *(const float2*)&xs[rr][2 * pw];
        float2 u1 = *(const float2*)&xs[rr][2 * pw + 2];
        pr[rr][0] = u0.x; pr[rr][1] = u0.y; pr[rr][2] = u1.x; pr[rr][3] = u1.y;
    }

    const float* wb = wfs + wavei * 80;
    s16x8 res;
    #pragma unroll
    for (int c8 = 0; c8 < 8; ++c8) {
        const float* wv = wb + c8 * 10;
        float a00 = 0.f, a01 = 0.f, a10 = 0.f, a11 = 0.f;
        #pragma unroll
        for (int ky = 0; ky < 3; ++ky)
            #pragma unroll
            for (int kx = 0; kx < 3; ++kx) {
                float wk = wv[ky * 3 + kx];
                a00 = fmaf(wk, pr[ky][kx],         a00);
                a01 = fmaf(wk, pr[ky][kx + 1],     a01);
                a10 = fmaf(wk, pr[ky + 1][kx],     a10);
                a11 = fmaf(wk, pr[ky + 1][kx + 1], a11);
            }
        float o = fmaxf(fmaxf(fmaxf(a00, a01), fmaxf(a10, a11)) + wv[9], 0.f);
        res[c8] = (short)f2bf(o);
    }
    *(s16x8*)(act1 + (((size_t)(b * 64 + ph)) * 64 + pw) * 32 + wavei * 8) = res;
}

// ---------------------------------------------------------------------------
// conv2: implicit-GEMM + BN + ReLU + pool, all-shift B via linear copy.
// ---------------------------------------------------------------------------
__global__ __launch_bounds__(256) void conv2_mfma(
    const unsigned short* __restrict__ xin,  // (64,64,64,32)
    const unsigned short* __restrict__ wp2S, // staged image 18432
    const float* __restrict__ cbv, const float* __restrict__ gg,
    const float* __restrict__ bnb, const float* __restrict__ mm,
    const float* __restrict__ vv,
    unsigned short* __restrict__ out)        // (64,32,32,64)
{
    constexpr int CI = 32, CO = 64, W = 64, WT = 66, CG = 4;
    constexpr int ASZ = 4 * WT * CI * 2;     // 16896
    constexpr int BSZ = 9 * CO * CI * 2;     // 36864
    constexpr int PH2 = 32, HPX = 4;

    __shared__ __align__(16) unsigned char sm[ASZ + BSZ];

    const int tid = threadIdx.x;
    const int wave = tid >> 6, lane = tid & 63;
    const int quad = lane >> 4, col = lane & 15;
    const int wm = wave;

    const int xcd  = blockIdx.x & 7;
    const int slot = blockIdx.x >> 3;
    const int hp = xcd * HPX + (slot % HPX);
    const int b  = slot / HPX;

    constexpr int NCHA = 4 * WT * CG;
    for (int ch = tid; ch < NCHA; ch += 256) {
        int r    = ch / (WT * CG);
        int rem  = ch % (WT * CG);
        int wp   = rem / CG;
        int slot_ = rem % CG;
        int g = slot_ ^ ((wp >> 1) & 3);
        int h = hp * 2 - 1 + r;
        int w = wp - 1;
        s16x8 val = {};
        if (h >= 0 && h < W && w >= 0 && w < W)
            val = *(const s16x8*)(xin + (((size_t)(b * W + h) * W + w) * CI + g * 8));
        *(s16x8*)(sm + ch * 16) = val;
    }
    for (int ch = tid; ch < 2304; ch += 256)
        *(s16x8*)(sm + ASZ + ch * 16) = *(const s16x8*)(wp2S + ch * 8);
    __syncthreads();

    f32x4 acc[2][4];
    #pragma unroll
    for (int i = 0; i < 2; ++i)
        #pragma unroll
        for (int j = 0; j < 4; ++j) acc[i][j] = (f32x4){0.f, 0.f, 0.f, 0.f};

    #pragma unroll
    for (int s = 0; s < 9; ++s) {
        const int dy = s / 3, dx = s % 3;
        const int g = quad;
        s16x8 a[2];
        #pragma unroll
        for (int mi = 0; mi < 2; ++mi) {
            int wp = wm * 16 + col + dx;
            int r  = mi + dy;
            int addr = (r * WT + wp) * (CI * 2) + ((g ^ ((wp >> 1) & 3)) << 4);
            a[mi] = *(const s16x8*)(sm + addr);
        }
        #pragma unroll
        for (int nf = 0; nf < 4; ++nf) {
            int co_l = nf * 16 + col;
            int row = co_l * 9 + s;
            int addr = ASZ + row * (CI * 2) + ((g ^ ((co_l >> 1) & 3)) << 4);
            s16x8 bf = *(const s16x8*)(sm + addr);
            acc[0][nf] = __builtin_amdgcn_mfma_f32_16x16x32_bf16(a[0], bf, acc[0][nf], 0, 0, 0);
            acc[1][nf] = __builtin_amdgcn_mfma_f32_16x16x32_bf16(a[1], bf, acc[1][nf], 0, 0, 0);
        }
    }

    #pragma unroll
    for (int nf = 0; nf < 4; ++nf) {
        int co = nf * 16 + col;
        float scl = gg[co] * rsqrtf(vv[co] + EPS);
        float sh  = (cbv[co] - mm[co]) * scl + bnb[co];
        #pragma unroll
        for (int pr = 0; pr < 2; ++pr) {
            float y0 = fmaf(acc[0][nf][2 * pr],     scl, sh);
            float y1 = fmaf(acc[0][nf][2 * pr + 1], scl, sh);
            float y2 = fmaf(acc[1][nf][2 * pr],     scl, sh);
            float y3 = fmaf(acc[1][nf][2 * pr + 1], scl, sh);
            float o = fmaxf(fmaxf(fmaxf(y0, y1), fmaxf(y2, y3)), 0.f);
            int pw = wm * 8 + quad * 2 + pr;
            out[((size_t)(b * PH2 + hp) * PH2 + pw) * CO + co] = f2bf(o);
        }
    }
}

// ---------------------------------------------------------------------------
// conv3: B per-wave from fragment-ordered wp3F (no B-LDS, 1 barrier).
// ---------------------------------------------------------------------------
__global__ __launch_bounds__(256) void conv3_mfma(
    const unsigned short* __restrict__ xin,  // (64,32,32,64)
    const unsigned short* __restrict__ wp3F, // frag-ordered 55296
    const float* __restrict__ cbv, const float* __restrict__ gg,
    const float* __restrict__ bnb, const float* __restrict__ mm,
    const float* __restrict__ vv,
    unsigned short* __restrict__ out)        // (64,16,16,96)
{
    constexpr int CI = 64, CO = 96, W = 32, WT = 34, CG = 8;
    constexpr int ASZ = 4 * WT * CI * 2;     // 17408
    constexpr int PH2 = 16, HPX = 2;

    __shared__ __align__(16) unsigned char sm[ASZ];

    const int tid = threadIdx.x;
    const int wave = tid >> 6, lane = tid & 63;
    const int quad = lane >> 4, col = lane & 15;
    const int wm = wave & 1, wn = wave >> 1;

    const int xcd  = blockIdx.x & 7;
    const int slot = blockIdx.x >> 3;
    const int hp = xcd * HPX + (slot % HPX);
    const int b  = slot / HPX;

    constexpr int NCHA = 4 * WT * CG;   // 1088
    for (int ch = tid; ch < NCHA; ch += 256) {
        int r    = ch / (WT * CG);
        int rem  = ch % (WT * CG);
        int wp   = rem / CG;
        int slot_ = rem % CG;
        int g = slot_ ^ (wp & 7);
        int h = hp * 2 - 1 + r;
        int w = wp - 1;
        s16x8 val = {};
        if (h >= 0 && h < W && w >= 0 && w < W)
            val = *(const s16x8*)(xin + (((size_t)(b * W + h) * W + w) * CI + g * 8));
        *(s16x8*)(sm + ch * 16) = val;
    }
    __syncthreads();

    f32x4 acc[2][3];
    #pragma unroll
    for (int i = 0; i < 2; ++i)
        #pragma unroll
        for (int j = 0; j < 3; ++j) acc[i][j] = (f32x4){0.f, 0.f, 0.f, 0.f};

    for (int s = 0; s < 9; ++s) {
        const int dy = s / 3, dx = s % 3;
        s16x8 bf[3][2];
        #pragma unroll
        for (int nf = 0; nf < 3; ++nf)
            #pragma unroll
            for (int kk = 0; kk < 2; ++kk) {
                int fidx = (((s * 2 + kk) * 6) + wn * 3 + nf) * 512 + lane * 8;
                bf[nf][kk] = *(const s16x8*)(wp3F + fidx);
            }
        #pragma unroll
        for (int kk = 0; kk < 2; ++kk) {
            const int g = kk * 4 + quad;
            s16x8 a[2];
            #pragma unroll
            for (int mi = 0; mi < 2; ++mi) {
                int wp = wm * 16 + col + dx;
                int r  = mi + dy;
                int addr = (r * WT + wp) * (CI * 2) + ((g ^ (wp & 7)) << 4);
                a[mi] = *(const s16x8*)(sm + addr);
            }
            #pragma unroll
            for (int nf = 0; nf < 3; ++nf) {
                acc[0][nf] = __builtin_amdgcn_mfma_f32_16x16x32_bf16(a[0], bf[nf][kk], acc[0][nf], 0, 0, 0);
                acc[1][nf] = __builtin_amdgcn_mfma_f32_16x16x32_bf16(a[1], bf[nf][kk], acc[1][nf], 0, 0, 0);
            }
        }
    }

    #pragma unroll
    for (int nf = 0; nf < 3; ++nf) {
        int co = (wn * 3 + nf) * 16 + col;
        float scl = gg[co] * rsqrtf(vv[co] + EPS);
        float sh  = (cbv[co] - mm[co]) * scl + bnb[co];
        #pragma unroll
        for (int pr = 0; pr < 2; ++pr) {
            float y0 = fmaf(acc[0][nf][2 * pr],     scl, sh);
            float y1 = fmaf(acc[0][nf][2 * pr + 1], scl, sh);
            float y2 = fmaf(acc[1][nf][2 * pr],     scl, sh);
            float y3 = fmaf(acc[1][nf][2 * pr + 1], scl, sh);
            float o = fmaxf(fmaxf(fmaxf(y0, y1), fmaxf(y2, y3)), 0.f);
            int pw = wm * 8 + quad * 2 + pr;
            out[((size_t)(b * PH2 + hp) * PH2 + pw) * CO + co] = f2bf(o);
        }
    }
}

// ---------------------------------------------------------------------------
// LRLC v4: B per-wave from fragment-ordered wpL3 (no B-LDS, 3 barriers).
// ---------------------------------------------------------------------------
__global__ __launch_bounds__(512) void lrlc_mfma4(
    const unsigned short* __restrict__ xin,  // (64,16,16,96) bf16
    const unsigned short* __restrict__ wpk3, // frag-ordered (442368)
    const float* __restrict__ bbias,         // (4,128)
    const float* __restrict__ cwh, const float* __restrict__ cww,
    unsigned short* __restrict__ actB)       // (64, 32768) bf16
{
    constexpr int CI = 96, WT = 18, NR = 10, CG = 12;
    constexpr int ASZ = NR * WT * CI * 2;    // 34560 B
    __shared__ __align__(16) unsigned char sm[ASZ];
    __shared__ float cwt[256][4];

    const int tid = threadIdx.x;
    const int wave = tid >> 6, lane = tid & 63;
    const int quad = lane >> 4, col = lane & 15;
    const int wm = wave & 1;
    const int g  = (wave >> 1) & 1;
    const int rp = wave >> 2;

    const int cbk = blockIdx.x & 3;
    const int mb  = (blockIdx.x >> 2) & 1;
    const int b   = blockIdx.x >> 3;

    if (tid < 256) {
        int h = tid >> 4, w = tid & 15;
        float e[4], mx = -1e30f;
        #pragma unroll
        for (int r = 0; r < 4; ++r) { e[r] = cwh[h * 4 + r] + cww[w * 4 + r]; mx = fmaxf(mx, e[r]); }
        float se = 0.f;
        #pragma unroll
        for (int r = 0; r < 4; ++r) { e[r] = expf(e[r] - mx); se += e[r]; }
        float inv = 1.f / se;
        #pragma unroll
        for (int r = 0; r < 4; ++r) cwt[tid][r] = e[r] * inv;
    }

    constexpr int NCHA = NR * WT * CG;  // 2160
    for (int ch = tid; ch < NCHA; ch += 512) {
        int r    = ch / (WT * CG);
        int rem  = ch % (WT * CG);
        int wp   = rem / CG, slot = rem % CG;
        int gg_ = slot ^ ((wp >> 1) & 3);
        int h = mb * 8 + r - 1;
        int w = wp - 1;
        s16x8 val = {};
        if (h >= 0 && h < 16 && w >= 0 && w < 16)
            val = *(const s16x8*)(xin + (((size_t)(b * 16 + h) * 16 + w) * CI + gg_ * 8));
        *(s16x8*)(sm + ch * 16) = val;
    }
    __syncthreads();

    f32x4 acc[4][2];
    #pragma unroll
    for (int i = 0; i < 4; ++i)
        #pragma unroll
        for (int j = 0; j < 2; ++j) acc[i][j] = (f32x4){0.f, 0.f, 0.f, 0.f};

    const int tbase = ((cbk * 2 + g) * 2 + rp);
    for (int s = 0; s < 9; ++s) {
        const int dy = s / 3, dx = s % 3;
        s16x8 bf[2][3];
        #pragma unroll
        for (int j = 0; j < 2; ++j)
            #pragma unroll
            for (int kk = 0; kk < 3; ++kk) {
                int fidx = ((s * 32 + tbase * 2 + j) * 3 + kk) * 512 + lane * 8;
                bf[j][kk] = *(const s16x8*)(wpk3 + fidx);
            }
        #pragma unroll
        for (int kk = 0; kk < 3; ++kk) {
            const int gg = kk * 4 + quad;
            s16x8 a[4];
            #pragma unroll
            for (int mi = 0; mi < 4; ++mi) {
                int mf = wm * 4 + mi;
                int r  = mf + dy;
                int wp = col + dx;
                int addr = (r * WT + wp) * (CI * 2) + ((gg ^ ((wp >> 1) & 3)) << 4);
                a[mi] = *(const s16x8*)(sm + addr);
            }
            #pragma unroll
            for (int mi = 0; mi < 4; ++mi)
                #pragma unroll
                for (int j = 0; j < 2; ++j)
                    acc[mi][j] = __builtin_amdgcn_mfma_f32_16x16x32_bf16(
                        a[mi], bf[j][kk], acc[mi][j], 0, 0, 0);
        }
    }
    __syncthreads();

    float* ldo = (float*)sm;   // [2][128][33]
    {
        const int c_lo = g * 16 + col;
        const int cg   = cbk * 32 + c_lo;
        float bbA = bbias[(rp * 2 + 0) * 128 + cg];
        float bbB = bbias[(rp * 2 + 1) * 128 + cg];
        #pragma unroll
        for (int mi = 0; mi < 4; ++mi) {
            int mf = wm * 4 + mi;
            #pragma unroll
            for (int rg = 0; rg < 4; ++rg) {
                int hwl = mf * 16 + quad * 4 + rg;
                int hwg = mb * 128 + hwl;
                float o = cwt[hwg][rp * 2]     * (acc[mi][0][rg] + bbA)
                        + cwt[hwg][rp * 2 + 1] * (acc[mi][1][rg] + bbB);
                ldo[(rp * 128 + hwl) * 33 + c_lo] = o;
            }
        }
    }
    __syncthreads();
    {
        int cl = tid >> 4;
        int sg = tid & 15;
        size_t base = (size_t)b * 32768 + (cbk * 32 + cl) * 256 + mb * 128 + sg * 8;
        s16x8 v;
        #pragma unroll
        for (int i = 0; i < 8; ++i) {
            int hw = sg * 8 + i;
            float o = ldo[hw * 33 + cl] + ldo[(128 + hw) * 33 + cl];
            v[i] = (short)f2bf(fmaxf(o, 0.f));
        }
        *(s16x8*)(actB + base) = v;
    }
}

// ---------------------------------------------------------------------------
// fc1 streaming: ONE 256-k chunk per block (grid 1024 = 8 xcd x 16 ks x 8 jt),
// staging fully front-loaded (24 independent loads -> single barrier -> 16
// MFMA). Both operands LDS-staged (R5-proven path). XCD-grouped ks so 8 jt
// blocks sharing an act chunk hit the same L2.
// ---------------------------------------------------------------------------
__global__ __launch_bounds__(256) void fc1_stream(
    const unsigned short* __restrict__ actB, // (64, 32768) bf16
    const float* __restrict__ w,             // (512, 32768) f32
    float* __restrict__ partial)             // (128, 512, 64)
{
    __shared__ __align__(16) unsigned short Wl[64 * 256];
    __shared__ __align__(16) unsigned short Al[64 * 256];

    const int tid = threadIdx.x;
    const int wave = tid >> 6, lane = tid & 63;
    const int quad = lane >> 4, col = lane & 15;
    const int wm = wave & 1, wn = wave >> 1;
    const int xcd  = blockIdx.x & 7;
    const int slot = blockIdx.x >> 3;        // 0..127, jt inner
    const int ks = xcd * 16 + (slot >> 3);   // 0..127
    const int jt = slot & 7;
    const int k0 = ks * 256;

    const int rt  = tid >> 2;
    const int seg = tid & 3;

    const float* wsrc = w + (size_t)(jt * 64 + rt) * 32768 + k0 + seg * 64;
    const unsigned short* asrc = actB + (size_t)rt * 32768 + k0 + seg * 64;

    #pragma unroll
    for (int u = 0; u < 8; ++u) {
        float4 f0 = *(const float4*)(wsrc + u * 8);
        float4 f1 = *(const float4*)(wsrc + u * 8 + 4);
        s16x8 av = *(const s16x8*)(asrc + u * 8);
        s16x8 v;
        v[0] = (short)f2bf(f0.x); v[1] = (short)f2bf(f0.y);
        v[2] = (short)f2bf(f0.z); v[3] = (short)f2bf(f0.w);
        v[4] = (short)f2bf(f1.x); v[5] = (short)f2bf(f1.y);
        v[6] = (short)f2bf(f1.z); v[7] = (short)f2bf(f1.w);
        int phys = (seg * 8 + u) ^ (rt & 7);
        *(s16x8*)(Wl + rt * 256 + phys * 8) = v;
        *(s16x8*)(Al + rt * 256 + phys * 8) = av;
    }
    __syncthreads();

    f32x4 acc[2][2];
    #pragma unroll
    for (int i = 0; i < 2; ++i)
        #pragma unroll
        for (int j = 0; j < 2; ++j) acc[i][j] = (f32x4){0.f, 0.f, 0.f, 0.f};

    #pragma unroll
    for (int kk = 0; kk < 8; ++kk) {
        const int gg = kk * 4 + quad;
        s16x8 a[2], bb[2];
        #pragma unroll
        for (int mf = 0; mf < 2; ++mf) {
            int j_l = wm * 32 + mf * 16 + col;
            a[mf] = *(const s16x8*)(Wl + j_l * 256 + ((gg ^ (j_l & 7)) << 3));
        }
        #pragma unroll
        for (int bg = 0; bg < 2; ++bg) {
            int b_l = wn * 32 + bg * 16 + col;
            bb[bg] = *(const s16x8*)(Al + b_l * 256 + ((gg ^ (b_l & 7)) << 3));
        }
        #pragma unroll
        for (int mf = 0; mf < 2; ++mf)
            #pragma unroll
            for (int bg = 0; bg < 2; ++bg)
                acc[mf][bg] = __builtin_amdgcn_mfma_f32_16x16x32_bf16(
                    a[mf], bb[bg], acc[mf][bg], 0, 0, 0);
    }
    #pragma unroll
    for (int mf = 0; mf < 2; ++mf)
        #pragma unroll
        for (int bg = 0; bg < 2; ++bg)
            #pragma unroll
            for (int r = 0; r < 4; ++r) {
                int j = jt * 64 + wm * 32 + mf * 16 + quad * 4 + r;
                int b = wn * 32 + bg * 16 + col;
                partial[((size_t)ks * 512 + j) * 64 + b] = acc[mf][bg][r];
            }
}

__global__ __launch_bounds__(256) void fc1_reduce6(
    const float* __restrict__ partial, const float* __restrict__ bias,
    float* __restrict__ out)             // (64,512)
{
    int idx = blockIdx.x * 256 + threadIdx.x;  // j*64 + b
    int b = idx & 63, j = idx >> 6;
    float a = bias[j];
    #pragma unroll 16
    for (int ks = 0; ks < 128; ++ks)
        a += partial[((size_t)ks * 512 + j) * 64 + b];
    out[b * 512 + j] = fmaxf(a, 0.f);
}

// ---------------------------------------------------------------------------
// fc2 wide: block per batch row; lane-split K with shuffle reduce.
// ---------------------------------------------------------------------------
__global__ __launch_bounds__(320) void fc2_w(
    const float* __restrict__ xin,   // (64,512)
    const float* __restrict__ w,     // (10,512)
    const float* __restrict__ bias,
    float* __restrict__ out)         // (64,10)
{
    const int b = blockIdx.x;
    const int tid = threadIdx.x;     // 0..319
    const int n = tid >> 5, l = tid & 31;
    const float* xr = xin + b * 512 + l * 16;
    const float* wr = w + n * 512 + l * 16;
    float s = 0.f;
    #pragma unroll
    for (int u = 0; u < 4; ++u) {
        float4 xv = *(const float4*)(xr + u * 4);
        float4 wv = *(const float4*)(wr + u * 4);
        s = fmaf(xv.x, wv.x, s); s = fmaf(xv.y, wv.y, s);
        s = fmaf(xv.z, wv.z, s); s = fmaf(xv.w, wv.w, s);
    }
    #pragma unroll
    for (int off = 16; off > 0; off >>= 1)
        s += __shfl_xor(s, off, 32);
    if (l == 0) out[b * 10 + n] = s + bias[n];
}

// ---------------------------------------------------------------------------
extern "C" void kernel_launch(void* const* d_in, const int* in_sizes, int n_in,
                              void* d_out, int out_size, void* d_ws, size_t ws_size,
                              hipStream_t stream) {
    const float* x   = (const float*)d_in[0];
    const float* c1w = (const float*)d_in[1];  const float* c1b = (const float*)d_in[2];
    const float* b1g = (const float*)d_in[3];  const float* b1b = (const float*)d_in[4];
    const float* b1m = (const float*)d_in[5];  const float* b1v = (const float*)d_in[6];
    const float* c2w = (const float*)d_in[7];  const float* c2b = (const float*)d_in[8];
    const float* b2g = (const float*)d_in[9];  const float* b2b = (const float*)d_in[10];
    const float* b2m = (const float*)d_in[11]; const float* b2v = (const float*)d_in[12];
    const float* c3w = (const float*)d_in[13]; const float* c3b = (const float*)d_in[14];
    const float* b3g = (const float*)d_in[15]; const float* b3b = (const float*)d_in[16];
    const float* b3m = (const float*)d_in[17]; const float* b3v = (const float*)d_in[18];
    const float* bw  = (const float*)d_in[19]; const float* bb  = (const float*)d_in[20];
    const float* cwh = (const float*)d_in[21]; const float* cww = (const float*)d_in[22];
    const float* f1w = (const float*)d_in[23]; const float* f1b = (const float*)d_in[24];
    const float* f2w = (const float*)d_in[25]; const float* f2b = (const float*)d_in[26];
    float* out = (float*)d_out;

    char* ws = (char*)d_ws;
    unsigned short* act1 = (unsigned short*)(ws + 0);           // [0,16M)
    unsigned short* act2 = (unsigned short*)(ws + 16777216);    // [16M,24M) dead before fc1
    unsigned short* act3 = (unsigned short*)(ws + 0);           // [0,3M)   (act1 dead)
    unsigned short* actB = (unsigned short*)(ws + 4194304);     // [4M,8M)
    float*          part = (float*)(ws + 8388608);              // [8M,24M) 128x512x64
    float*          fc1o = (float*)(ws + 0);                    // [0,128K) (act3 dead)
    unsigned short* wp2S = (unsigned short*)(ws + 25165824);    //  36,864 B
    unsigned short* wp3F = (unsigned short*)(ws + 25202688);    // 110,592 B
    unsigned short* wpL3 = (unsigned short*)(ws + 25313280);    // 884,736 B

    repack_conv1<<<6112, 256, 0, stream>>>(x, c1w, c1b, b1g, b1b, b1m, b1v,
                                           c2w, c3w, bw, act1, wp2S, wp3F, wpL3);

    conv2_mfma<<<2048, 256, 0, stream>>>(act1, wp2S, c2b, b2g, b2b, b2m, b2v, act2);

    conv3_mfma<<<1024, 256, 0, stream>>>(act2, wp3F, c3b, b3g, b3b, b3m, b3v, act3);

    lrlc_mfma4<<<512, 512, 0, stream>>>(act3, wpL3, bb, cwh, cww, actB);

    fc1_stream<<<1024, 256, 0, stream>>>(actB, f1w, part);
    fc1_reduce6<<<128, 256, 0, stream>>>(part, f1b, fc1o);
    fc2_w<<<64, 320, 0, stream>>>(fc1o, f2w, f2b, out);
}